// Round 1
// baseline (31915.823 us; speedup 1.0000x reference)
//
#include <hip/hip_runtime.h>
#include <hip/hip_cooperative_groups.h>

namespace cg = cooperative_groups;

// LSTM T=1000 N=32 D=320 H=1024 L=3 on MI355X.
// Persistent cooperative kernel: wavefront over (layer,t), grid.sync() per wave.
// Weights RESIDENT on-chip: 8 K-iters/wave in VGPRs (128 VGPR/thread) +
// 8 K-iters/wave in LDS (128 KiB/block). c-state + bias resident in registers.
// bf16 MFMA 16x16x32; weights pre-packed into B-fragment order in d_ws.
//
// ws layout (bytes):
//   [0,         20480000)  x as bf16            (T*N*320)
//   [20480000,  65044480)  packed B fragments   (22,282,240 bf16)
//   [65044480,  65437696)  h ping-pong bf16     (L * 2 * N*H)
//   [65437696,  65830912)  c state fp32         (L * N*H)
//   [65830912,  65880064)  bias fp32            (L * 4096)

#define T_ 1000
#define N_ 32
#define D_ 320
#define H_ 1024
#define NH (N_ * H_)

typedef __bf16 bf16;
typedef bf16 bf16x8 __attribute__((ext_vector_type(8)));
typedef bf16 bf16x4 __attribute__((ext_vector_type(4)));
typedef float floatx4 __attribute__((ext_vector_type(4)));

__device__ __forceinline__ float sigm(float x) { return 1.f / (1.f + __expf(-x)); }
__device__ __forceinline__ float tanh_(float x) {
  float e = __expf(2.f * x);
  return 1.f - 2.f / (e + 1.f);
}

// ---- prep: x (fp32) -> bf16 ----
__global__ __launch_bounds__(256) void prep_x(const float4* __restrict__ x,
                                              bf16x4* __restrict__ xb) {
  int idx = blockIdx.x * 256 + threadIdx.x;  // 2,560,000 threads, 4 elems each
  float4 v = x[idx];
  bf16x4 o;
  o[0] = (bf16)v.x; o[1] = (bf16)v.y; o[2] = (bf16)v.z; o[3] = (bf16)v.w;
  xb[idx] = o;
}

// ---- prep: pack W = [w_ih_l ; w_hh_l] (K x 4096) into MFMA B-fragment order.
// packed idx (within layer) = ((g*64 + jt)*KB + kb)*512 + lane*8 + i
//   k = kb*32 + (lane>>4)*8 + i ; j = g*1024 + jt*16 + (lane&15)
__global__ __launch_bounds__(256) void prep_pack(const float* __restrict__ w_ih0,
                                                 const float* __restrict__ w_ihr,
                                                 const float* __restrict__ w_hh,
                                                 bf16* __restrict__ packed) {
  int idx = blockIdx.x * 256 + threadIdx.x;  // 22,282,240 total
  int l, r;
  if (idx < 5505024)       { l = 0; r = idx; }
  else if (idx < 13893632) { l = 1; r = idx - 5505024; }
  else                     { l = 2; r = idx - 13893632; }
  const int i    = r & 7;
  const int lane = (r >> 3) & 63;
  const int q    = r >> 9;
  int kb, p;
  if (l == 0) { kb = q % 42; p = q / 42; }   // KB=42 (10 x-blocks + 32 h-blocks)
  else        { kb = q & 63; p = q >> 6; }   // KB=64 (32 + 32)
  const int jt = p & 63;
  const int g  = p >> 6;
  const int k  = kb * 32 + ((lane >> 4) << 3) + i;
  const int j  = (g << 10) + jt * 16 + (lane & 15);
  const int KX = (l == 0) ? 320 : 1024;
  float v;
  if (k < KX) {
    v = (l == 0) ? w_ih0[(size_t)k * 4096 + j]
                 : w_ihr[(size_t)(l - 1) * 4194304 + (size_t)k * 4096 + j];
  } else {
    v = w_hh[(size_t)l * 4194304 + (size_t)(k - KX) * 4096 + j];
  }
  packed[idx] = (bf16)v;
}

// ---- prep: h0 -> hbuf slot 1 (t=0 reads slot (t-1)&1 == 1), c0 -> c_state, bias sum
__global__ __launch_bounds__(256) void prep_state(const float* __restrict__ h0,
                                                  const float* __restrict__ c0,
                                                  const float* __restrict__ b_ih,
                                                  const float* __restrict__ b_hh,
                                                  bf16* __restrict__ hbuf,
                                                  float* __restrict__ c_state,
                                                  float* __restrict__ bias) {
  int idx = blockIdx.x * 256 + threadIdx.x;  // 98,304 threads
  int l = idx >> 15;                         // NH = 32768
  int rem = idx & 32767;
  hbuf[(size_t)l * 2 * NH + NH + rem] = (bf16)h0[idx];
  c_state[idx] = c0[idx];
  if (idx < 12288) bias[idx] = b_ih[idx] + b_hh[idx];
}

// ======================= persistent cooperative kernel =======================
// grid = 192 blocks (3 layers x 64 j-tiles), 256 threads (4 waves, K-split).
// 1 block/CU (155,648 B LDS). Loop wv = 0..1001 with grid.sync() per wave.
__global__ __launch_bounds__(256, 1) void lstm_persist(
    const bf16* __restrict__ xb, const bf16* __restrict__ packed,
    bf16* hbuf,                     // read AND written (no restrict)
    const float* __restrict__ c_state, const float* __restrict__ bias,
    float* __restrict__ out) {
  const int l  = blockIdx.x >> 6;
  const int jt = blockIdx.x & 63;
  const int tid  = threadIdx.x;
  const int wid  = tid >> 6;
  const int lane = tid & 63;
  const int quad = lane >> 4;
  const int lo   = lane & 15;

  const int KB   = (l == 0) ? 42 : 64;
  const int KXb  = (l == 0) ? 10 : 32;
  const int xstr = (l == 0) ? D_ : H_;
  const size_t lbase = (l == 0) ? 0 : (l == 1 ? 5505024u : 13893632u);
  const int gstr = 64 * KB * 512;                 // per-gate stride (elements)
  const bf16* Bb = packed + lbase + (size_t)jt * KB * 512;

  // LDS: weight slice for K-iters n=8.. (per wave), + cross-wave reduce buffer.
  __shared__ bf16x8  wlds[4][8][4][64];           // [wid][n-8][g][lane]  128 KiB
  __shared__ floatx4 red[3][2][4][64];            // [wid-1][mt][g][lane]  24 KiB

  // ---- one-time: weights -> VGPRs (n<8) and LDS (n>=8). Own-wave slice only:
  // no __syncthreads needed (each wave reads only wlds[wid][...]).
  bf16x8 wreg[8][4];
#pragma unroll
  for (int n = 0; n < 8; ++n) {
    const int kb = wid + 4 * n;
    const bf16* bp = Bb + kb * 512 + lane * 8;
#pragma unroll
    for (int g = 0; g < 4; ++g)
      wreg[n][g] = *(const bf16x8*)(bp + (size_t)g * gstr);
  }
  for (int n = 8; wid + 4 * n < KB; ++n) {
    const int kb = wid + 4 * n;
    const bf16* bp = Bb + kb * 512 + lane * 8;
#pragma unroll
    for (int g = 0; g < 4; ++g)
      wlds[wid][n - 8][g][lane] = *(const bf16x8*)(bp + (size_t)g * gstr);
  }

  // ---- one-time: bias + c into registers (block owns its (l,jt) slice).
  const int j_h = jt * 16 + lo;
  const float bI = bias[l * 4096 + j_h];
  const float bF = bias[l * 4096 + 1024 + j_h];
  const float bG = bias[l * 4096 + 2048 + j_h];
  const float bO = bias[l * 4096 + 3072 + j_h];
  float creg[2][4];
#pragma unroll
  for (int mt = 0; mt < 2; ++mt)
#pragma unroll
    for (int r = 0; r < 4; ++r)
      creg[mt][r] = c_state[l * NH + (mt * 16 + quad * 4 + r) * H_ + j_h];

  const int arow0 = lo * xstr + quad * 8;
  const int arow1 = (16 + lo) * xstr + quad * 8;
  const int hrow0 = lo * H_ + quad * 8;
  const int hrow1 = (16 + lo) * H_ + quad * 8;

  cg::grid_group grid = cg::this_grid();

  for (int wv = 0; wv < T_ + 2; ++wv) {
    const int t = wv - l;
    if (t >= 0 && t < T_) {                       // block-uniform predicate
      const bf16* xsrc = (l == 0)
          ? (xb + (size_t)t * (N_ * D_))
          : (hbuf + (size_t)(l - 1) * 2 * NH + (size_t)(t & 1) * NH);
      const bf16* hsrc = hbuf + (size_t)l * 2 * NH + (size_t)((t - 1) & 1) * NH;

      floatx4 acc[2][4];
      const floatx4 zero = {0.f, 0.f, 0.f, 0.f};
#pragma unroll
      for (int mt = 0; mt < 2; ++mt)
#pragma unroll
        for (int g = 0; g < 4; ++g) acc[mt][g] = zero;

      // register-resident K iters (static indices -> wreg stays in VGPRs)
#pragma unroll
      for (int n = 0; n < 8; ++n) {
        const int kb = wid + 4 * n;
        bf16x8 a0, a1;
        if (kb < KXb) {
          const bf16* p = xsrc + kb * 32;
          a0 = *(const bf16x8*)(p + arow0);
          a1 = *(const bf16x8*)(p + arow1);
        } else {
          const bf16* p = hsrc + (kb - KXb) * 32;
          a0 = *(const bf16x8*)(p + hrow0);
          a1 = *(const bf16x8*)(p + hrow1);
        }
        acc[0][0] = __builtin_amdgcn_mfma_f32_16x16x32_bf16(a0, wreg[n][0], acc[0][0], 0, 0, 0);
        acc[0][1] = __builtin_amdgcn_mfma_f32_16x16x32_bf16(a0, wreg[n][1], acc[0][1], 0, 0, 0);
        acc[0][2] = __builtin_amdgcn_mfma_f32_16x16x32_bf16(a0, wreg[n][2], acc[0][2], 0, 0, 0);
        acc[0][3] = __builtin_amdgcn_mfma_f32_16x16x32_bf16(a0, wreg[n][3], acc[0][3], 0, 0, 0);
        acc[1][0] = __builtin_amdgcn_mfma_f32_16x16x32_bf16(a1, wreg[n][0], acc[1][0], 0, 0, 0);
        acc[1][1] = __builtin_amdgcn_mfma_f32_16x16x32_bf16(a1, wreg[n][1], acc[1][1], 0, 0, 0);
        acc[1][2] = __builtin_amdgcn_mfma_f32_16x16x32_bf16(a1, wreg[n][2], acc[1][2], 0, 0, 0);
        acc[1][3] = __builtin_amdgcn_mfma_f32_16x16x32_bf16(a1, wreg[n][3], acc[1][3], 0, 0, 0);
      }
      // LDS-resident K iters
      for (int n = 8; wid + 4 * n < KB; ++n) {
        const int kb = wid + 4 * n;
        bf16x8 a0, a1;
        if (kb < KXb) {
          const bf16* p = xsrc + kb * 32;
          a0 = *(const bf16x8*)(p + arow0);
          a1 = *(const bf16x8*)(p + arow1);
        } else {
          const bf16* p = hsrc + (kb - KXb) * 32;
          a0 = *(const bf16x8*)(p + hrow0);
          a1 = *(const bf16x8*)(p + hrow1);
        }
        const bf16x8 b0 = wlds[wid][n - 8][0][lane];
        const bf16x8 b1 = wlds[wid][n - 8][1][lane];
        const bf16x8 b2 = wlds[wid][n - 8][2][lane];
        const bf16x8 b3 = wlds[wid][n - 8][3][lane];
        acc[0][0] = __builtin_amdgcn_mfma_f32_16x16x32_bf16(a0, b0, acc[0][0], 0, 0, 0);
        acc[0][1] = __builtin_amdgcn_mfma_f32_16x16x32_bf16(a0, b1, acc[0][1], 0, 0, 0);
        acc[0][2] = __builtin_amdgcn_mfma_f32_16x16x32_bf16(a0, b2, acc[0][2], 0, 0, 0);
        acc[0][3] = __builtin_amdgcn_mfma_f32_16x16x32_bf16(a0, b3, acc[0][3], 0, 0, 0);
        acc[1][0] = __builtin_amdgcn_mfma_f32_16x16x32_bf16(a1, b0, acc[1][0], 0, 0, 0);
        acc[1][1] = __builtin_amdgcn_mfma_f32_16x16x32_bf16(a1, b1, acc[1][1], 0, 0, 0);
        acc[1][2] = __builtin_amdgcn_mfma_f32_16x16x32_bf16(a1, b2, acc[1][2], 0, 0, 0);
        acc[1][3] = __builtin_amdgcn_mfma_f32_16x16x32_bf16(a1, b3, acc[1][3], 0, 0, 0);
      }

      // K-split reduction: waves 1..3 publish acc; wave 0 keeps its own in regs.
      if (wid != 0) {
#pragma unroll
        for (int mt = 0; mt < 2; ++mt)
#pragma unroll
          for (int g = 0; g < 4; ++g) red[wid - 1][mt][g][lane] = acc[mt][g];
      }
      __syncthreads();

      if (wid == 0) {
        bf16* hdst = hbuf + (size_t)l * 2 * NH + (size_t)(t & 1) * NH;
#pragma unroll
        for (int mt = 0; mt < 2; ++mt) {
          floatx4 sI = acc[mt][0] + red[0][mt][0][lane] + red[1][mt][0][lane] + red[2][mt][0][lane];
          floatx4 sF = acc[mt][1] + red[0][mt][1][lane] + red[1][mt][1][lane] + red[2][mt][1][lane];
          floatx4 sG = acc[mt][2] + red[0][mt][2][lane] + red[1][mt][2][lane] + red[2][mt][2][lane];
          floatx4 sO = acc[mt][3] + red[0][mt][3][lane] + red[1][mt][3][lane] + red[2][mt][3][lane];
#pragma unroll
          for (int r = 0; r < 4; ++r) {
            const int m = mt * 16 + quad * 4 + r;
            const float ii = sigm(sI[r] + bI);
            const float ff = sigm(sF[r] + bF);
            const float gg = tanh_(sG[r] + bG);
            const float oo = sigm(sO[r] + bO);
            const float c = ff * creg[mt][r] + ii * gg;
            creg[mt][r] = c;
            const float h = oo * tanh_(c);
            const int off = m * H_ + j_h;
            hdst[off] = (bf16)h;
            if (l == 2) out[(size_t)t * NH + off] = h;
            if (t == T_ - 1) {
              out[32768000 + l * NH + off] = h;   // hT (fp32, pre-rounding)
              out[32866304 + l * NH + off] = c;   // cT
            }
          }
        }
      }
    }
    grid.sync();   // publishes h(t) grid-wide; next wave consumes it
  }
}

// ======================= fallback: launch-per-wave step =======================
__global__ __launch_bounds__(256) void lstm_step(int wv,
                                                 const bf16* __restrict__ xb,
                                                 const bf16* __restrict__ packed,
                                                 bf16* __restrict__ hbuf,
                                                 float* __restrict__ c_state,
                                                 const float* __restrict__ bias,
                                                 float* __restrict__ out) {
  const int l  = blockIdx.x >> 6;
  const int jt = blockIdx.x & 63;
  const int t  = wv - l;
  if (t < 0 || t >= T_) return;

  const int tid  = threadIdx.x;
  const int wid  = tid >> 6;
  const int lane = tid & 63;
  const int quad = lane >> 4;
  const int lo   = lane & 15;

  const int KB   = (l == 0) ? 42 : 64;
  const int KXb  = (l == 0) ? 10 : 32;
  const int xstr = (l == 0) ? D_ : H_;
  const bf16* xsrc = (l == 0) ? (xb + (size_t)t * (N_ * D_))
                              : (hbuf + (size_t)(l - 1) * 2 * NH + (size_t)(t & 1) * NH);
  const bf16* hsrc = hbuf + (size_t)l * 2 * NH + (size_t)((t - 1) & 1) * NH;
  const size_t lbase = (l == 0) ? 0 : (l == 1 ? 5505024u : 13893632u);
  const int gstr = 64 * KB * 512;
  const bf16* Bb = packed + lbase + (size_t)jt * KB * 512;

  floatx4 acc[2][4];
  const floatx4 zero = {0.f, 0.f, 0.f, 0.f};
#pragma unroll
  for (int mt = 0; mt < 2; ++mt)
#pragma unroll
    for (int g = 0; g < 4; ++g) acc[mt][g] = zero;

  const int arow0 = lo * xstr + quad * 8;
  const int arow1 = (16 + lo) * xstr + quad * 8;
  const int hrow0 = lo * H_ + quad * 8;
  const int hrow1 = (16 + lo) * H_ + quad * 8;

#pragma unroll 2
  for (int kb = wid; kb < KB; kb += 4) {
    bf16x8 a0, a1;
    if (kb < KXb) {
      const bf16* p = xsrc + kb * 32;
      a0 = *(const bf16x8*)(p + arow0);
      a1 = *(const bf16x8*)(p + arow1);
    } else {
      const bf16* p = hsrc + (kb - KXb) * 32;
      a0 = *(const bf16x8*)(p + hrow0);
      a1 = *(const bf16x8*)(p + hrow1);
    }
    const bf16* bp = Bb + kb * 512 + lane * 8;
    bf16x8 b0 = *(const bf16x8*)(bp);
    bf16x8 b1 = *(const bf16x8*)(bp + gstr);
    bf16x8 b2 = *(const bf16x8*)(bp + 2 * gstr);
    bf16x8 b3 = *(const bf16x8*)(bp + 3 * gstr);
    acc[0][0] = __builtin_amdgcn_mfma_f32_16x16x32_bf16(a0, b0, acc[0][0], 0, 0, 0);
    acc[0][1] = __builtin_amdgcn_mfma_f32_16x16x32_bf16(a0, b1, acc[0][1], 0, 0, 0);
    acc[0][2] = __builtin_amdgcn_mfma_f32_16x16x32_bf16(a0, b2, acc[0][2], 0, 0, 0);
    acc[0][3] = __builtin_amdgcn_mfma_f32_16x16x32_bf16(a0, b3, acc[0][3], 0, 0, 0);
    acc[1][0] = __builtin_amdgcn_mfma_f32_16x16x32_bf16(a1, b0, acc[1][0], 0, 0, 0);
    acc[1][1] = __builtin_amdgcn_mfma_f32_16x16x32_bf16(a1, b1, acc[1][1], 0, 0, 0);
    acc[1][2] = __builtin_amdgcn_mfma_f32_16x16x32_bf16(a1, b2, acc[1][2], 0, 0, 0);
    acc[1][3] = __builtin_amdgcn_mfma_f32_16x16x32_bf16(a1, b3, acc[1][3], 0, 0, 0);
  }

  __shared__ float red[4][2][4][4][64];
#pragma unroll
  for (int mt = 0; mt < 2; ++mt)
#pragma unroll
    for (int g = 0; g < 4; ++g)
#pragma unroll
      for (int r = 0; r < 4; ++r) red[wid][mt][g][r][lane] = acc[mt][g][r];
  __syncthreads();
  if (wid != 0) return;

  const int j_h = jt * 16 + lo;
  const float bI = bias[l * 4096 + j_h];
  const float bF = bias[l * 4096 + 1024 + j_h];
  const float bG = bias[l * 4096 + 2048 + j_h];
  const float bO = bias[l * 4096 + 3072 + j_h];
  float* cst = c_state + l * NH;
  bf16* hdst = hbuf + (size_t)l * 2 * NH + (size_t)(t & 1) * NH;

#pragma unroll
  for (int mt = 0; mt < 2; ++mt)
#pragma unroll
    for (int r = 0; r < 4; ++r) {
      const int m = mt * 16 + quad * 4 + r;
      float s0 = 0.f, s1 = 0.f, s2 = 0.f, s3 = 0.f;
#pragma unroll
      for (int w2 = 0; w2 < 4; ++w2) {
        s0 += red[w2][mt][0][r][lane];
        s1 += red[w2][mt][1][r][lane];
        s2 += red[w2][mt][2][r][lane];
        s3 += red[w2][mt][3][r][lane];
      }
      const float ii = sigm(s0 + bI);
      const float ff = sigm(s1 + bF);
      const float gg = tanh_(s2 + bG);
      const float oo = sigm(s3 + bO);
      const int off = m * H_ + j_h;
      const float c = ff * cst[off] + ii * gg;
      cst[off] = c;
      const float h = oo * tanh_(c);
      hdst[off] = (bf16)h;
      if (l == 2) out[(size_t)t * NH + off] = h;
      if (t == T_ - 1) {
        out[32768000 + l * NH + off] = h;
        out[32866304 + l * NH + off] = c;
      }
    }
}

extern "C" void kernel_launch(void* const* d_in, const int* in_sizes, int n_in,
                              void* d_out, int out_size, void* d_ws, size_t ws_size,
                              hipStream_t stream) {
  (void)in_sizes; (void)n_in; (void)out_size; (void)ws_size;
  const float* x     = (const float*)d_in[0];
  const float* h0    = (const float*)d_in[1];
  const float* c0    = (const float*)d_in[2];
  const float* w_ih0 = (const float*)d_in[3];
  const float* w_ihr = (const float*)d_in[4];
  const float* w_hh  = (const float*)d_in[5];
  const float* b_ih  = (const float*)d_in[6];
  const float* b_hh  = (const float*)d_in[7];
  float* out = (float*)d_out;
  char* ws = (char*)d_ws;

  bf16*  xb      = (bf16*)(ws + 0);
  bf16*  packed  = (bf16*)(ws + 20480000);
  bf16*  hbuf    = (bf16*)(ws + 65044480);
  float* c_state = (float*)(ws + 65437696);
  float* bias    = (float*)(ws + 65830912);

  hipLaunchKernelGGL(prep_x, dim3(10000), dim3(256), 0, stream,
                     (const float4*)x, (bf16x4*)xb);
  hipLaunchKernelGGL(prep_pack, dim3(87040), dim3(256), 0, stream,
                     w_ih0, w_ihr, w_hh, packed);
  hipLaunchKernelGGL(prep_state, dim3(384), dim3(256), 0, stream,
                     h0, c0, b_ih, b_hh, hbuf, c_state, bias);

  const bf16*  xb_c  = (const bf16*)xb;
  const bf16*  pk_c  = (const bf16*)packed;
  bf16*        hb    = hbuf;
  const float* cs_c  = (const float*)c_state;
  const float* bi_c  = (const float*)bias;
  float*       out_p = out;
  void* args[6] = {&xb_c, &pk_c, &hb, &cs_c, &bi_c, &out_p};
  hipError_t e = hipLaunchCooperativeKernel((const void*)lstm_persist,
                                            dim3(192), dim3(256), args, 0, stream);
  if (e != hipSuccess) {
    (void)hipGetLastError();  // clear error state, fall back to per-wave launches
    for (int wv = 0; wv < T_ + 2; ++wv)
      hipLaunchKernelGGL(lstm_step, dim3(192), dim3(256), 0, stream, wv,
                         xb_c, pk_c, hb, c_state, bias, out);
  }
}

// Round 2
// 20015.758 us; speedup vs baseline: 1.5945x; 1.5945x over previous
//
#include <hip/hip_runtime.h>

// LSTM T=1000 N=32 D=320 H=1024 L=3 on MI355X.
// Persistent cooperative kernel; hand-rolled device-scope grid barrier
// (slot-array + agent fences) instead of cg::grid_group::sync() (31.6 us/sync!).
// Weights RESIDENT on-chip: 8 K-iters/wave in VGPRs + 8 K-iters/wave in LDS.
// c-state + bias resident in registers.
//
// ws layout (bytes):
//   [0,         20480000)  x as bf16            (T*N*320)
//   [20480000,  65044480)  packed B fragments   (22,282,240 bf16)
//   [65044480,  65437696)  h ping-pong bf16     (L * 2 * N*H)
//   [65437696,  65830912)  c state fp32         (L * N*H)
//   [65830912,  65880064)  bias fp32            (L * 4096)
//   [65880064,  65881088)  barrier slots u32    (192 used, 256 zeroed)

#define T_ 1000
#define N_ 32
#define D_ 320
#define H_ 1024
#define NH (N_ * H_)

typedef __bf16 bf16;
typedef bf16 bf16x8 __attribute__((ext_vector_type(8)));
typedef bf16 bf16x4 __attribute__((ext_vector_type(4)));
typedef float floatx4 __attribute__((ext_vector_type(4)));

__device__ __forceinline__ float sigm(float x) { return 1.f / (1.f + __expf(-x)); }
__device__ __forceinline__ float tanh_(float x) {
  float e = __expf(2.f * x);
  return 1.f - 2.f / (e + 1.f);
}

// ---- prep: x (fp32) -> bf16 ----
__global__ __launch_bounds__(256) void prep_x(const float4* __restrict__ x,
                                              bf16x4* __restrict__ xb) {
  int idx = blockIdx.x * 256 + threadIdx.x;  // 2,560,000 threads, 4 elems each
  float4 v = x[idx];
  bf16x4 o;
  o[0] = (bf16)v.x; o[1] = (bf16)v.y; o[2] = (bf16)v.z; o[3] = (bf16)v.w;
  xb[idx] = o;
}

// ---- prep: pack W = [w_ih_l ; w_hh_l] (K x 4096) into MFMA B-fragment order.
// packed idx (within layer) = ((g*64 + jt)*KB + kb)*512 + lane*8 + i
//   k = kb*32 + (lane>>4)*8 + i ; j = g*1024 + jt*16 + (lane&15)
__global__ __launch_bounds__(256) void prep_pack(const float* __restrict__ w_ih0,
                                                 const float* __restrict__ w_ihr,
                                                 const float* __restrict__ w_hh,
                                                 bf16* __restrict__ packed) {
  int idx = blockIdx.x * 256 + threadIdx.x;  // 22,282,240 total
  int l, r;
  if (idx < 5505024)       { l = 0; r = idx; }
  else if (idx < 13893632) { l = 1; r = idx - 5505024; }
  else                     { l = 2; r = idx - 13893632; }
  const int i    = r & 7;
  const int lane = (r >> 3) & 63;
  const int q    = r >> 9;
  int kb, p;
  if (l == 0) { kb = q % 42; p = q / 42; }   // KB=42 (10 x-blocks + 32 h-blocks)
  else        { kb = q & 63; p = q >> 6; }   // KB=64 (32 + 32)
  const int jt = p & 63;
  const int g  = p >> 6;
  const int k  = kb * 32 + ((lane >> 4) << 3) + i;
  const int j  = (g << 10) + jt * 16 + (lane & 15);
  const int KX = (l == 0) ? 320 : 1024;
  float v;
  if (k < KX) {
    v = (l == 0) ? w_ih0[(size_t)k * 4096 + j]
                 : w_ihr[(size_t)(l - 1) * 4194304 + (size_t)k * 4096 + j];
  } else {
    v = w_hh[(size_t)l * 4194304 + (size_t)(k - KX) * 4096 + j];
  }
  packed[idx] = (bf16)v;
}

// ---- prep: h0 -> hbuf slot 1, c0 -> c_state, bias sum, zero barrier slots
__global__ __launch_bounds__(256) void prep_state(const float* __restrict__ h0,
                                                  const float* __restrict__ c0,
                                                  const float* __restrict__ b_ih,
                                                  const float* __restrict__ b_hh,
                                                  bf16* __restrict__ hbuf,
                                                  float* __restrict__ c_state,
                                                  float* __restrict__ bias,
                                                  unsigned* __restrict__ slots) {
  int idx = blockIdx.x * 256 + threadIdx.x;  // 98,304 threads
  int l = idx >> 15;                         // NH = 32768
  int rem = idx & 32767;
  hbuf[(size_t)l * 2 * NH + NH + rem] = (bf16)h0[idx];
  c_state[idx] = c0[idx];
  if (idx < 12288) bias[idx] = b_ih[idx] + b_hh[idx];
  if (idx < 256) slots[idx] = 0u;
}

// ======================= persistent cooperative kernel =======================
// grid = 192 blocks (3 layers x 64 j-tiles), 256 threads (4 waves, K-split).
// 1 block/CU (155,648 B LDS). Loop wv = 0..1001; hand-rolled grid barrier.
__global__ __launch_bounds__(256, 1) void lstm_persist(
    const bf16* __restrict__ xb, const bf16* __restrict__ packed,
    bf16* hbuf,                     // read AND written (no restrict)
    const float* __restrict__ c_state, const float* __restrict__ bias,
    unsigned* slots,
    float* __restrict__ out) {
  const int l  = blockIdx.x >> 6;
  const int jt = blockIdx.x & 63;
  const int tid  = threadIdx.x;
  const int wid  = tid >> 6;
  const int lane = tid & 63;
  const int quad = lane >> 4;
  const int lo   = lane & 15;

  const int KB   = (l == 0) ? 42 : 64;
  const int KXb  = (l == 0) ? 10 : 32;
  const int xstr = (l == 0) ? D_ : H_;
  const size_t lbase = (l == 0) ? 0 : (l == 1 ? 5505024u : 13893632u);
  const int gstr = 64 * KB * 512;                 // per-gate stride (elements)
  const bf16* Bb = packed + lbase + (size_t)jt * KB * 512;

  // LDS: weight slice for K-iters n=8.. (per wave), + cross-wave reduce buffer.
  __shared__ bf16x8  wlds[4][8][4][64];           // [wid][n-8][g][lane]  128 KiB
  __shared__ floatx4 red[3][2][4][64];            // [wid-1][mt][g][lane]  24 KiB

  // ---- one-time: weights -> VGPRs (n<8) and LDS (n>=8). Own-wave slice only.
  bf16x8 wreg[8][4];
#pragma unroll
  for (int n = 0; n < 8; ++n) {
    const int kb = wid + 4 * n;
    const bf16* bp = Bb + kb * 512 + lane * 8;
#pragma unroll
    for (int g = 0; g < 4; ++g)
      wreg[n][g] = *(const bf16x8*)(bp + (size_t)g * gstr);
  }
  for (int n = 8; wid + 4 * n < KB; ++n) {
    const int kb = wid + 4 * n;
    const bf16* bp = Bb + kb * 512 + lane * 8;
#pragma unroll
    for (int g = 0; g < 4; ++g)
      wlds[wid][n - 8][g][lane] = *(const bf16x8*)(bp + (size_t)g * gstr);
  }

  // ---- one-time: bias + c into registers (block owns its (l,jt) slice).
  const int j_h = jt * 16 + lo;
  const float bI = bias[l * 4096 + j_h];
  const float bF = bias[l * 4096 + 1024 + j_h];
  const float bG = bias[l * 4096 + 2048 + j_h];
  const float bO = bias[l * 4096 + 3072 + j_h];
  float creg[2][4];
#pragma unroll
  for (int mt = 0; mt < 2; ++mt)
#pragma unroll
    for (int r = 0; r < 4; ++r)
      creg[mt][r] = c_state[l * NH + (mt * 16 + quad * 4 + r) * H_ + j_h];

  const int arow0 = lo * xstr + quad * 8;
  const int arow1 = (16 + lo) * xstr + quad * 8;
  const int hrow0 = lo * H_ + quad * 8;
  const int hrow1 = (16 + lo) * H_ + quad * 8;

  for (int wv = 0; wv < T_ + 2; ++wv) {
    const int t = wv - l;
    if (t >= 0 && t < T_) {                       // block-uniform predicate
      const bf16* xsrc = (l == 0)
          ? (xb + (size_t)t * (N_ * D_))
          : (hbuf + (size_t)(l - 1) * 2 * NH + (size_t)(t & 1) * NH);
      const bf16* hsrc = hbuf + (size_t)l * 2 * NH + (size_t)((t - 1) & 1) * NH;

      floatx4 acc[2][4];
      const floatx4 zero = {0.f, 0.f, 0.f, 0.f};
#pragma unroll
      for (int mt = 0; mt < 2; ++mt)
#pragma unroll
        for (int g = 0; g < 4; ++g) acc[mt][g] = zero;

      // register-resident K iters
#pragma unroll
      for (int n = 0; n < 8; ++n) {
        const int kb = wid + 4 * n;
        bf16x8 a0, a1;
        if (kb < KXb) {
          const bf16* p = xsrc + kb * 32;
          a0 = *(const bf16x8*)(p + arow0);
          a1 = *(const bf16x8*)(p + arow1);
        } else {
          const bf16* p = hsrc + (kb - KXb) * 32;
          a0 = *(const bf16x8*)(p + hrow0);
          a1 = *(const bf16x8*)(p + hrow1);
        }
        acc[0][0] = __builtin_amdgcn_mfma_f32_16x16x32_bf16(a0, wreg[n][0], acc[0][0], 0, 0, 0);
        acc[0][1] = __builtin_amdgcn_mfma_f32_16x16x32_bf16(a0, wreg[n][1], acc[0][1], 0, 0, 0);
        acc[0][2] = __builtin_amdgcn_mfma_f32_16x16x32_bf16(a0, wreg[n][2], acc[0][2], 0, 0, 0);
        acc[0][3] = __builtin_amdgcn_mfma_f32_16x16x32_bf16(a0, wreg[n][3], acc[0][3], 0, 0, 0);
        acc[1][0] = __builtin_amdgcn_mfma_f32_16x16x32_bf16(a1, wreg[n][0], acc[1][0], 0, 0, 0);
        acc[1][1] = __builtin_amdgcn_mfma_f32_16x16x32_bf16(a1, wreg[n][1], acc[1][1], 0, 0, 0);
        acc[1][2] = __builtin_amdgcn_mfma_f32_16x16x32_bf16(a1, wreg[n][2], acc[1][2], 0, 0, 0);
        acc[1][3] = __builtin_amdgcn_mfma_f32_16x16x32_bf16(a1, wreg[n][3], acc[1][3], 0, 0, 0);
      }
      // LDS-resident K iters
      for (int n = 8; wid + 4 * n < KB; ++n) {
        const int kb = wid + 4 * n;
        bf16x8 a0, a1;
        if (kb < KXb) {
          const bf16* p = xsrc + kb * 32;
          a0 = *(const bf16x8*)(p + arow0);
          a1 = *(const bf16x8*)(p + arow1);
        } else {
          const bf16* p = hsrc + (kb - KXb) * 32;
          a0 = *(const bf16x8*)(p + hrow0);
          a1 = *(const bf16x8*)(p + hrow1);
        }
        const bf16x8 b0 = wlds[wid][n - 8][0][lane];
        const bf16x8 b1 = wlds[wid][n - 8][1][lane];
        const bf16x8 b2 = wlds[wid][n - 8][2][lane];
        const bf16x8 b3 = wlds[wid][n - 8][3][lane];
        acc[0][0] = __builtin_amdgcn_mfma_f32_16x16x32_bf16(a0, b0, acc[0][0], 0, 0, 0);
        acc[0][1] = __builtin_amdgcn_mfma_f32_16x16x32_bf16(a0, b1, acc[0][1], 0, 0, 0);
        acc[0][2] = __builtin_amdgcn_mfma_f32_16x16x32_bf16(a0, b2, acc[0][2], 0, 0, 0);
        acc[0][3] = __builtin_amdgcn_mfma_f32_16x16x32_bf16(a0, b3, acc[0][3], 0, 0, 0);
        acc[1][0] = __builtin_amdgcn_mfma_f32_16x16x32_bf16(a1, b0, acc[1][0], 0, 0, 0);
        acc[1][1] = __builtin_amdgcn_mfma_f32_16x16x32_bf16(a1, b1, acc[1][1], 0, 0, 0);
        acc[1][2] = __builtin_amdgcn_mfma_f32_16x16x32_bf16(a1, b2, acc[1][2], 0, 0, 0);
        acc[1][3] = __builtin_amdgcn_mfma_f32_16x16x32_bf16(a1, b3, acc[1][3], 0, 0, 0);
      }

      // K-split reduction: waves 1..3 publish acc; wave 0 keeps its own in regs.
      if (wid != 0) {
#pragma unroll
        for (int mt = 0; mt < 2; ++mt)
#pragma unroll
          for (int g = 0; g < 4; ++g) red[wid - 1][mt][g][lane] = acc[mt][g];
      }
      __syncthreads();

      if (wid == 0) {
        bf16* hdst = hbuf + (size_t)l * 2 * NH + (size_t)(t & 1) * NH;
#pragma unroll
        for (int mt = 0; mt < 2; ++mt) {
          floatx4 sI = acc[mt][0] + red[0][mt][0][lane] + red[1][mt][0][lane] + red[2][mt][0][lane];
          floatx4 sF = acc[mt][1] + red[0][mt][1][lane] + red[1][mt][1][lane] + red[2][mt][1][lane];
          floatx4 sG = acc[mt][2] + red[0][mt][2][lane] + red[1][mt][2][lane] + red[2][mt][2][lane];
          floatx4 sO = acc[mt][3] + red[0][mt][3][lane] + red[1][mt][3][lane] + red[2][mt][3][lane];
#pragma unroll
          for (int r = 0; r < 4; ++r) {
            const int m = mt * 16 + quad * 4 + r;
            const float ii = sigm(sI[r] + bI);
            const float ff = sigm(sF[r] + bF);
            const float gg = tanh_(sG[r] + bG);
            const float oo = sigm(sO[r] + bO);
            const float c = ff * creg[mt][r] + ii * gg;
            creg[mt][r] = c;
            const float h = oo * tanh_(c);
            const int off = m * H_ + j_h;
            hdst[off] = (bf16)h;                           // flushed by release fence
            if (l == 2) __builtin_nontemporal_store(h, &out[(size_t)t * NH + off]);
            if (t == T_ - 1) {
              __builtin_nontemporal_store(h, &out[32768000 + l * NH + off]);  // hT
              __builtin_nontemporal_store(c, &out[32866304 + l * NH + off]);  // cT
            }
          }
        }
      }
    }

    // ---- hand-rolled grid barrier (wave 0 only; waves 1-3 wait at sync) ----
    if (wid == 0) {
      // publish: drain + write back dirty L2 (h stores), then bump own slot.
      __builtin_amdgcn_fence(__ATOMIC_RELEASE, "agent");
      if (lane == 0)
        __hip_atomic_store(&slots[blockIdx.x], (unsigned)(wv + 1),
                           __ATOMIC_RELAXED, __HIP_MEMORY_SCOPE_AGENT);
      // wait: 64 lanes scan all 192 slots with L2-bypassing relaxed loads.
      const unsigned tgt = (unsigned)(wv + 1);
      for (;;) {
        unsigned a = __hip_atomic_load(&slots[lane],       __ATOMIC_RELAXED, __HIP_MEMORY_SCOPE_AGENT);
        unsigned b = __hip_atomic_load(&slots[lane + 64],  __ATOMIC_RELAXED, __HIP_MEMORY_SCOPE_AGENT);
        unsigned c = __hip_atomic_load(&slots[lane + 128], __ATOMIC_RELAXED, __HIP_MEMORY_SCOPE_AGENT);
        if (__all(a >= tgt && b >= tgt && c >= tgt)) break;
      }
      // make remote h visible: invalidate this CU's L1 + XCD L2.
      __builtin_amdgcn_fence(__ATOMIC_ACQUIRE, "agent");
    }
    __syncthreads();
  }
}

// ======================= fallback: launch-per-wave step =======================
__global__ __launch_bounds__(256) void lstm_step(int wv,
                                                 const bf16* __restrict__ xb,
                                                 const bf16* __restrict__ packed,
                                                 bf16* __restrict__ hbuf,
                                                 float* __restrict__ c_state,
                                                 const float* __restrict__ bias,
                                                 float* __restrict__ out) {
  const int l  = blockIdx.x >> 6;
  const int jt = blockIdx.x & 63;
  const int t  = wv - l;
  if (t < 0 || t >= T_) return;

  const int tid  = threadIdx.x;
  const int wid  = tid >> 6;
  const int lane = tid & 63;
  const int quad = lane >> 4;
  const int lo   = lane & 15;

  const int KB   = (l == 0) ? 42 : 64;
  const int KXb  = (l == 0) ? 10 : 32;
  const int xstr = (l == 0) ? D_ : H_;
  const bf16* xsrc = (l == 0) ? (xb + (size_t)t * (N_ * D_))
                              : (hbuf + (size_t)(l - 1) * 2 * NH + (size_t)(t & 1) * NH);
  const bf16* hsrc = hbuf + (size_t)l * 2 * NH + (size_t)((t - 1) & 1) * NH;
  const size_t lbase = (l == 0) ? 0 : (l == 1 ? 5505024u : 13893632u);
  const int gstr = 64 * KB * 512;
  const bf16* Bb = packed + lbase + (size_t)jt * KB * 512;

  floatx4 acc[2][4];
  const floatx4 zero = {0.f, 0.f, 0.f, 0.f};
#pragma unroll
  for (int mt = 0; mt < 2; ++mt)
#pragma unroll
    for (int g = 0; g < 4; ++g) acc[mt][g] = zero;

  const int arow0 = lo * xstr + quad * 8;
  const int arow1 = (16 + lo) * xstr + quad * 8;
  const int hrow0 = lo * H_ + quad * 8;
  const int hrow1 = (16 + lo) * H_ + quad * 8;

#pragma unroll 2
  for (int kb = wid; kb < KB; kb += 4) {
    bf16x8 a0, a1;
    if (kb < KXb) {
      const bf16* p = xsrc + kb * 32;
      a0 = *(const bf16x8*)(p + arow0);
      a1 = *(const bf16x8*)(p + arow1);
    } else {
      const bf16* p = hsrc + (kb - KXb) * 32;
      a0 = *(const bf16x8*)(p + hrow0);
      a1 = *(const bf16x8*)(p + hrow1);
    }
    const bf16* bp = Bb + kb * 512 + lane * 8;
    bf16x8 b0 = *(const bf16x8*)(bp);
    bf16x8 b1 = *(const bf16x8*)(bp + gstr);
    bf16x8 b2 = *(const bf16x8*)(bp + 2 * gstr);
    bf16x8 b3 = *(const bf16x8*)(bp + 3 * gstr);
    acc[0][0] = __builtin_amdgcn_mfma_f32_16x16x32_bf16(a0, b0, acc[0][0], 0, 0, 0);
    acc[0][1] = __builtin_amdgcn_mfma_f32_16x16x32_bf16(a0, b1, acc[0][1], 0, 0, 0);
    acc[0][2] = __builtin_amdgcn_mfma_f32_16x16x32_bf16(a0, b2, acc[0][2], 0, 0, 0);
    acc[0][3] = __builtin_amdgcn_mfma_f32_16x16x32_bf16(a0, b3, acc[0][3], 0, 0, 0);
    acc[1][0] = __builtin_amdgcn_mfma_f32_16x16x32_bf16(a1, b0, acc[1][0], 0, 0, 0);
    acc[1][1] = __builtin_amdgcn_mfma_f32_16x16x32_bf16(a1, b1, acc[1][1], 0, 0, 0);
    acc[1][2] = __builtin_amdgcn_mfma_f32_16x16x32_bf16(a1, b2, acc[1][2], 0, 0, 0);
    acc[1][3] = __builtin_amdgcn_mfma_f32_16x16x32_bf16(a1, b3, acc[1][3], 0, 0, 0);
  }

  __shared__ float red[4][2][4][4][64];
#pragma unroll
  for (int mt = 0; mt < 2; ++mt)
#pragma unroll
    for (int g = 0; g < 4; ++g)
#pragma unroll
      for (int r = 0; r < 4; ++r) red[wid][mt][g][r][lane] = acc[mt][g][r];
  __syncthreads();
  if (wid != 0) return;

  const int j_h = jt * 16 + lo;
  const float bI = bias[l * 4096 + j_h];
  const float bF = bias[l * 4096 + 1024 + j_h];
  const float bG = bias[l * 4096 + 2048 + j_h];
  const float bO = bias[l * 4096 + 3072 + j_h];
  float* cst = c_state + l * NH;
  bf16* hdst = hbuf + (size_t)l * 2 * NH + (size_t)(t & 1) * NH;

#pragma unroll
  for (int mt = 0; mt < 2; ++mt)
#pragma unroll
    for (int r = 0; r < 4; ++r) {
      const int m = mt * 16 + quad * 4 + r;
      float s0 = 0.f, s1 = 0.f, s2 = 0.f, s3 = 0.f;
#pragma unroll
      for (int w2 = 0; w2 < 4; ++w2) {
        s0 += red[w2][mt][0][r][lane];
        s1 += red[w2][mt][1][r][lane];
        s2 += red[w2][mt][2][r][lane];
        s3 += red[w2][mt][3][r][lane];
      }
      const float ii = sigm(s0 + bI);
      const float ff = sigm(s1 + bF);
      const float gg = tanh_(s2 + bG);
      const float oo = sigm(s3 + bO);
      const int off = m * H_ + j_h;
      const float c = ff * cst[off] + ii * gg;
      cst[off] = c;
      const float h = oo * tanh_(c);
      hdst[off] = (bf16)h;
      if (l == 2) out[(size_t)t * NH + off] = h;
      if (t == T_ - 1) {
        out[32768000 + l * NH + off] = h;
        out[32866304 + l * NH + off] = c;
      }
    }
}

extern "C" void kernel_launch(void* const* d_in, const int* in_sizes, int n_in,
                              void* d_out, int out_size, void* d_ws, size_t ws_size,
                              hipStream_t stream) {
  (void)in_sizes; (void)n_in; (void)out_size;
  const float* x     = (const float*)d_in[0];
  const float* h0    = (const float*)d_in[1];
  const float* c0    = (const float*)d_in[2];
  const float* w_ih0 = (const float*)d_in[3];
  const float* w_ihr = (const float*)d_in[4];
  const float* w_hh  = (const float*)d_in[5];
  const float* b_ih  = (const float*)d_in[6];
  const float* b_hh  = (const float*)d_in[7];
  float* out = (float*)d_out;
  char* ws = (char*)d_ws;

  bf16*     xb      = (bf16*)(ws + 0);
  bf16*     packed  = (bf16*)(ws + 20480000);
  bf16*     hbuf    = (bf16*)(ws + 65044480);
  float*    c_state = (float*)(ws + 65437696);
  float*    bias    = (float*)(ws + 65830912);
  unsigned* slots   = (unsigned*)(ws + 65880064);
  const bool have_slots = ws_size >= 65880064u + 1024u;

  hipLaunchKernelGGL(prep_x, dim3(10000), dim3(256), 0, stream,
                     (const float4*)x, (bf16x4*)xb);
  hipLaunchKernelGGL(prep_pack, dim3(87040), dim3(256), 0, stream,
                     w_ih0, w_ihr, w_hh, packed);
  hipLaunchKernelGGL(prep_state, dim3(384), dim3(256), 0, stream,
                     h0, c0, b_ih, b_hh, hbuf, c_state, bias,
                     have_slots ? slots : (unsigned*)c_state /*unused dummy write target guard*/);

  const bf16*  xb_c  = (const bf16*)xb;
  const bf16*  pk_c  = (const bf16*)packed;
  bf16*        hb    = hbuf;
  const float* cs_c  = (const float*)c_state;
  const float* bi_c  = (const float*)bias;
  unsigned*    sl    = slots;
  float*       out_p = out;

  hipError_t e = hipErrorUnknown;
  if (have_slots) {
    void* args[7] = {&xb_c, &pk_c, &hb, &cs_c, &bi_c, &sl, &out_p};
    e = hipLaunchCooperativeKernel((const void*)lstm_persist,
                                   dim3(192), dim3(256), args, 0, stream);
  }
  if (e != hipSuccess) {
    (void)hipGetLastError();  // clear error state, fall back to per-wave launches
    for (int wv = 0; wv < T_ + 2; ++wv)
      hipLaunchKernelGGL(lstm_step, dim3(192), dim3(256), 0, stream, wv,
                         xb_c, pk_c, hb, c_state, bias, out);
  }
}

// Round 3
// 13463.312 us; speedup vs baseline: 2.3706x; 1.4867x over previous
//
#include <hip/hip_runtime.h>

// LSTM T=1000 N=32 D=320 H=1024 L=3 on MI355X.
// Persistent cooperative kernel; fence-free grid barrier:
//   h exchange via sc0/sc1 (LLC-coherent) stores + relaxed agent atomic loads,
//   slot array + poll, NO buffer_wbl2/buffer_inv cache maintenance.
// Weights RESIDENT on-chip: 8 K-iters/wave in VGPRs + 8 K-iters/wave in LDS.
// c-state + bias in registers; epilogue distributed across all 4 waves.
//
// ws layout (bytes):
//   [0,         20480000)  x as bf16            (T*N*320)
//   [20480000,  65044480)  packed B fragments   (22,282,240 bf16)
//   [65044480,  65437696)  h ping-pong bf16     (L * 2 * N*H)
//   [65437696,  65830912)  c state fp32         (L * N*H)
//   [65830912,  65880064)  bias fp32            (L * 4096)
//   [65880064,  65881088)  barrier slots u32    (192 used, 256 zeroed)

#define T_ 1000
#define N_ 32
#define D_ 320
#define H_ 1024
#define NH (N_ * H_)

typedef __bf16 bf16;
typedef bf16 bf16x8 __attribute__((ext_vector_type(8)));
typedef bf16 bf16x4 __attribute__((ext_vector_type(4)));
typedef float floatx4 __attribute__((ext_vector_type(4)));
typedef unsigned long long u64;

__device__ __forceinline__ float sigm(float x) { return 1.f / (1.f + __expf(-x)); }
__device__ __forceinline__ float tanh_(float x) {
  float e = __expf(2.f * x);
  return 1.f - 2.f / (e + 1.f);
}

// Coherent (LLC) 16B load as 2x relaxed agent-scope 8B atomics -> dwordx2 sc1.
__device__ __forceinline__ bf16x8 ldh8(const bf16* p) {
  u64 q0 = __hip_atomic_load((const u64*)p, __ATOMIC_RELAXED, __HIP_MEMORY_SCOPE_AGENT);
  u64 q1 = __hip_atomic_load(((const u64*)p) + 1, __ATOMIC_RELAXED, __HIP_MEMORY_SCOPE_AGENT);
  union { u64 q[2]; bf16x8 v; } u;
  u.q[0] = q0; u.q[1] = q1;
  return u.v;
}

// Coherent (LLC write-through) 2B store: bypasses the non-coherent XCD L2.
__device__ __forceinline__ void sth(bf16* p, float h) {
  union { __bf16 b; unsigned short s; } u;
  u.b = (__bf16)h;
  unsigned v = u.s;
  asm volatile("global_store_short %0, %1, off sc0 sc1" :: "v"(p), "v"(v) : "memory");
}

// ---- prep: x (fp32) -> bf16 ----
__global__ __launch_bounds__(256) void prep_x(const float4* __restrict__ x,
                                              bf16x4* __restrict__ xb) {
  int idx = blockIdx.x * 256 + threadIdx.x;  // 2,560,000 threads, 4 elems each
  float4 v = x[idx];
  bf16x4 o;
  o[0] = (bf16)v.x; o[1] = (bf16)v.y; o[2] = (bf16)v.z; o[3] = (bf16)v.w;
  xb[idx] = o;
}

// ---- prep: pack W = [w_ih_l ; w_hh_l] (K x 4096) into MFMA B-fragment order.
__global__ __launch_bounds__(256) void prep_pack(const float* __restrict__ w_ih0,
                                                 const float* __restrict__ w_ihr,
                                                 const float* __restrict__ w_hh,
                                                 bf16* __restrict__ packed) {
  int idx = blockIdx.x * 256 + threadIdx.x;  // 22,282,240 total
  int l, r;
  if (idx < 5505024)       { l = 0; r = idx; }
  else if (idx < 13893632) { l = 1; r = idx - 5505024; }
  else                     { l = 2; r = idx - 13893632; }
  const int i    = r & 7;
  const int lane = (r >> 3) & 63;
  const int q    = r >> 9;
  int kb, p;
  if (l == 0) { kb = q % 42; p = q / 42; }   // KB=42 (10 x-blocks + 32 h-blocks)
  else        { kb = q & 63; p = q >> 6; }   // KB=64 (32 + 32)
  const int jt = p & 63;
  const int g  = p >> 6;
  const int k  = kb * 32 + ((lane >> 4) << 3) + i;
  const int j  = (g << 10) + jt * 16 + (lane & 15);
  const int KX = (l == 0) ? 320 : 1024;
  float v;
  if (k < KX) {
    v = (l == 0) ? w_ih0[(size_t)k * 4096 + j]
                 : w_ihr[(size_t)(l - 1) * 4194304 + (size_t)k * 4096 + j];
  } else {
    v = w_hh[(size_t)l * 4194304 + (size_t)(k - KX) * 4096 + j];
  }
  packed[idx] = (bf16)v;
}

// ---- prep: h0 -> hbuf slot 1, c0 -> c_state, bias sum, zero barrier slots
__global__ __launch_bounds__(256) void prep_state(const float* __restrict__ h0,
                                                  const float* __restrict__ c0,
                                                  const float* __restrict__ b_ih,
                                                  const float* __restrict__ b_hh,
                                                  bf16* __restrict__ hbuf,
                                                  float* __restrict__ c_state,
                                                  float* __restrict__ bias,
                                                  unsigned* __restrict__ slots) {
  int idx = blockIdx.x * 256 + threadIdx.x;  // 98,304 threads
  int l = idx >> 15;                         // NH = 32768
  int rem = idx & 32767;
  hbuf[(size_t)l * 2 * NH + NH + rem] = (bf16)h0[idx];
  c_state[idx] = c0[idx];
  if (idx < 12288) bias[idx] = b_ih[idx] + b_hh[idx];
  if (idx < 256) slots[idx] = 0u;
}

// ======================= persistent cooperative kernel =======================
// grid = 192 blocks (3 layers x 64 j-tiles), 256 threads (4 waves, K-split).
// 1 block/CU. Loop wv = 0..1001; fence-free slot barrier.
__global__ __launch_bounds__(256, 1) void lstm_persist(
    const bf16* __restrict__ xb, const bf16* __restrict__ packed,
    bf16* hbuf,                     // read AND written (no restrict)
    const float* __restrict__ c_state, const float* __restrict__ bias,
    unsigned* slots,
    float* __restrict__ out) {
  const int l  = blockIdx.x >> 6;
  const int jt = blockIdx.x & 63;
  const int tid  = threadIdx.x;
  const int wid  = __builtin_amdgcn_readfirstlane(tid >> 6);  // wave-uniform -> SGPR
  const int lane = tid & 63;
  const int quad = lane >> 4;
  const int lo   = lane & 15;

  const int KB   = (l == 0) ? 42 : 64;
  const int KXb  = (l == 0) ? 10 : 32;
  const int xstr = (l == 0) ? D_ : H_;
  const size_t lbase = (l == 0) ? 0 : (l == 1 ? 5505024u : 13893632u);
  const int gstr = 64 * KB * 512;                 // per-gate stride (elements)
  const bf16* Bb = packed + lbase + (size_t)jt * KB * 512;

  // LDS: weight slice for K-iters n=8..15 (per wave) + cross-wave reduce buffer
  // (3 of 4 rows per wave; each wave keeps its own row r==wid in registers).
  __shared__ bf16x8 wlds[4][8][4][64];            // [wid][n-8][g][lane]  128 KiB
  __shared__ float  red[4][2][4][3][64];          // [wid][mt][g][ri][lane] 24 KiB

  // ---- one-time: weights -> VGPRs (n<8) and LDS (n>=8). Own-wave slice only.
  bf16x8 wreg[8][4];
#pragma unroll
  for (int n = 0; n < 8; ++n) {
    const int kb = wid + 4 * n;
    const bf16* bp = Bb + kb * 512 + lane * 8;
#pragma unroll
    for (int g = 0; g < 4; ++g)
      wreg[n][g] = *(const bf16x8*)(bp + (size_t)g * gstr);
  }
  for (int n = 8; wid + 4 * n < KB; ++n) {
    const int kb = wid + 4 * n;
    const bf16* bp = Bb + kb * 512 + lane * 8;
#pragma unroll
    for (int g = 0; g < 4; ++g)
      wlds[wid][n - 8][g][lane] = *(const bf16x8*)(bp + (size_t)g * gstr);
  }

  // ---- one-time: bias + c into registers. This wave owns rows r = wid.
  const int j_h = jt * 16 + lo;
  const float bI = bias[l * 4096 + j_h];
  const float bF = bias[l * 4096 + 1024 + j_h];
  const float bG = bias[l * 4096 + 2048 + j_h];
  const float bO = bias[l * 4096 + 3072 + j_h];
  float creg[2];
#pragma unroll
  for (int mt = 0; mt < 2; ++mt)
    creg[mt] = c_state[l * NH + (mt * 16 + quad * 4 + wid) * H_ + j_h];

  const int arow0 = lo * xstr + quad * 8;
  const int arow1 = (16 + lo) * xstr + quad * 8;
  const int hrow0 = lo * H_ + quad * 8;
  const int hrow1 = (16 + lo) * H_ + quad * 8;

  for (int wv = 0; wv < T_ + 2; ++wv) {
    const int t = wv - l;
    if (t >= 0 && t < T_) {                       // block-uniform predicate
      const bf16* xsrc = (l == 0)
          ? (xb + (size_t)t * (N_ * D_))
          : (hbuf + (size_t)(l - 1) * 2 * NH + (size_t)(t & 1) * NH);
      const bf16* hsrc = hbuf + (size_t)l * 2 * NH + (size_t)((t - 1) & 1) * NH;

      floatx4 acc[2][4];
      const floatx4 zero = {0.f, 0.f, 0.f, 0.f};
#pragma unroll
      for (int mt = 0; mt < 2; ++mt)
#pragma unroll
        for (int g = 0; g < 4; ++g) acc[mt][g] = zero;

      // K-loop in chunks of 4 iters: batch-issue 8 coherent loads, then MFMA.
#pragma unroll
      for (int c = 0; c < 4; ++c) {
        bf16x8 A0[4], A1[4];
#pragma unroll
        for (int u = 0; u < 4; ++u) {
          const int n = 4 * c + u;
          const int kb = wid + 4 * n;
          if (kb < KB) {
            const bf16* p;
            int r0, r1;
            if (kb < KXb) { p = xsrc + kb * 32; r0 = arow0; r1 = arow1; }
            else          { p = hsrc + (kb - KXb) * 32; r0 = hrow0; r1 = hrow1; }
            A0[u] = ldh8(p + r0);
            A1[u] = ldh8(p + r1);
          }
        }
#pragma unroll
        for (int u = 0; u < 4; ++u) {
          const int n = 4 * c + u;
          const int kb = wid + 4 * n;
          if (kb < KB) {
            bf16x8 b0, b1, b2, b3;
            if (n < 8) {                           // static n: stays in VGPRs
              b0 = wreg[n][0]; b1 = wreg[n][1]; b2 = wreg[n][2]; b3 = wreg[n][3];
            } else {
              b0 = wlds[wid][n - 8][0][lane];
              b1 = wlds[wid][n - 8][1][lane];
              b2 = wlds[wid][n - 8][2][lane];
              b3 = wlds[wid][n - 8][3][lane];
            }
            acc[0][0] = __builtin_amdgcn_mfma_f32_16x16x32_bf16(A0[u], b0, acc[0][0], 0, 0, 0);
            acc[0][1] = __builtin_amdgcn_mfma_f32_16x16x32_bf16(A0[u], b1, acc[0][1], 0, 0, 0);
            acc[0][2] = __builtin_amdgcn_mfma_f32_16x16x32_bf16(A0[u], b2, acc[0][2], 0, 0, 0);
            acc[0][3] = __builtin_amdgcn_mfma_f32_16x16x32_bf16(A0[u], b3, acc[0][3], 0, 0, 0);
            acc[1][0] = __builtin_amdgcn_mfma_f32_16x16x32_bf16(A1[u], b0, acc[1][0], 0, 0, 0);
            acc[1][1] = __builtin_amdgcn_mfma_f32_16x16x32_bf16(A1[u], b1, acc[1][1], 0, 0, 0);
            acc[1][2] = __builtin_amdgcn_mfma_f32_16x16x32_bf16(A1[u], b2, acc[1][2], 0, 0, 0);
            acc[1][3] = __builtin_amdgcn_mfma_f32_16x16x32_bf16(A1[u], b3, acc[1][3], 0, 0, 0);
          }
        }
      }

      // publish partial sums for rows this wave does NOT own (r != wid)
#pragma unroll
      for (int mt = 0; mt < 2; ++mt)
#pragma unroll
        for (int g = 0; g < 4; ++g)
#pragma unroll
          for (int r = 0; r < 4; ++r)
            if (r != wid) red[wid][mt][g][r - (r > wid ? 1 : 0)][lane] = acc[mt][g][r];
      __syncthreads();

      // distributed epilogue: wave `wid` handles rows r = wid (both mt).
      bf16* hdst = hbuf + (size_t)l * 2 * NH + (size_t)(t & 1) * NH;
#pragma unroll
      for (int mt = 0; mt < 2; ++mt) {
        float s[4];
#pragma unroll
        for (int g = 0; g < 4; ++g) {
          float sum = (wid == 0) ? acc[mt][g][0]
                    : (wid == 1) ? acc[mt][g][1]
                    : (wid == 2) ? acc[mt][g][2] : acc[mt][g][3];
#pragma unroll
          for (int w2 = 0; w2 < 4; ++w2)
            if (w2 != wid)
              sum += red[w2][mt][g][wid - (wid > w2 ? 1 : 0)][lane];
          s[g] = sum;
        }
        const float ii = sigm(s[0] + bI);
        const float ff = sigm(s[1] + bF);
        const float gg = tanh_(s[2] + bG);
        const float oo = sigm(s[3] + bO);
        const float c = ff * creg[mt] + ii * gg;
        creg[mt] = c;
        const float h = oo * tanh_(c);
        const int off = (mt * 16 + quad * 4 + wid) * H_ + j_h;
        sth(hdst + off, h);                       // sc0 sc1 write-through to LLC
        if (l == 2) __builtin_nontemporal_store(h, &out[(size_t)t * NH + off]);
        if (t == T_ - 1) {
          __builtin_nontemporal_store(h, &out[32768000 + l * NH + off]);  // hT
          __builtin_nontemporal_store(c, &out[32866304 + l * NH + off]);  // cT
        }
      }
    }

    // ---- fence-free grid barrier. __syncthreads drains vmcnt(0) per wave,
    // so all sc1 h-stores are in the LLC before the slot publish.
    __syncthreads();
    if (wid == 0) {
      __hip_atomic_store(&slots[blockIdx.x], (unsigned)(wv + 1),
                         __ATOMIC_RELAXED, __HIP_MEMORY_SCOPE_AGENT);
      const unsigned tgt = (unsigned)(wv + 1);
      for (;;) {
        unsigned a = __hip_atomic_load(&slots[lane],       __ATOMIC_RELAXED, __HIP_MEMORY_SCOPE_AGENT);
        unsigned b = __hip_atomic_load(&slots[lane + 64],  __ATOMIC_RELAXED, __HIP_MEMORY_SCOPE_AGENT);
        unsigned c = __hip_atomic_load(&slots[lane + 128], __ATOMIC_RELAXED, __HIP_MEMORY_SCOPE_AGENT);
        if (__all((a >= tgt) && (b >= tgt) && (c >= tgt))) break;
      }
    }
    __syncthreads();
  }
}

// ======================= fallback: launch-per-wave step =======================
__global__ __launch_bounds__(256) void lstm_step(int wv,
                                                 const bf16* __restrict__ xb,
                                                 const bf16* __restrict__ packed,
                                                 bf16* __restrict__ hbuf,
                                                 float* __restrict__ c_state,
                                                 const float* __restrict__ bias,
                                                 float* __restrict__ out) {
  const int l  = blockIdx.x >> 6;
  const int jt = blockIdx.x & 63;
  const int t  = wv - l;
  if (t < 0 || t >= T_) return;

  const int tid  = threadIdx.x;
  const int wid  = tid >> 6;
  const int lane = tid & 63;
  const int quad = lane >> 4;
  const int lo   = lane & 15;

  const int KB   = (l == 0) ? 42 : 64;
  const int KXb  = (l == 0) ? 10 : 32;
  const int xstr = (l == 0) ? D_ : H_;
  const bf16* xsrc = (l == 0) ? (xb + (size_t)t * (N_ * D_))
                              : (hbuf + (size_t)(l - 1) * 2 * NH + (size_t)(t & 1) * NH);
  const bf16* hsrc = hbuf + (size_t)l * 2 * NH + (size_t)((t - 1) & 1) * NH;
  const size_t lbase = (l == 0) ? 0 : (l == 1 ? 5505024u : 13893632u);
  const int gstr = 64 * KB * 512;
  const bf16* Bb = packed + lbase + (size_t)jt * KB * 512;

  floatx4 acc[2][4];
  const floatx4 zero = {0.f, 0.f, 0.f, 0.f};
#pragma unroll
  for (int mt = 0; mt < 2; ++mt)
#pragma unroll
    for (int g = 0; g < 4; ++g) acc[mt][g] = zero;

  const int arow0 = lo * xstr + quad * 8;
  const int arow1 = (16 + lo) * xstr + quad * 8;
  const int hrow0 = lo * H_ + quad * 8;
  const int hrow1 = (16 + lo) * H_ + quad * 8;

#pragma unroll 2
  for (int kb = wid; kb < KB; kb += 4) {
    bf16x8 a0, a1;
    if (kb < KXb) {
      const bf16* p = xsrc + kb * 32;
      a0 = *(const bf16x8*)(p + arow0);
      a1 = *(const bf16x8*)(p + arow1);
    } else {
      const bf16* p = hsrc + (kb - KXb) * 32;
      a0 = *(const bf16x8*)(p + hrow0);
      a1 = *(const bf16x8*)(p + hrow1);
    }
    const bf16* bp = Bb + kb * 512 + lane * 8;
    bf16x8 b0 = *(const bf16x8*)(bp);
    bf16x8 b1 = *(const bf16x8*)(bp + gstr);
    bf16x8 b2 = *(const bf16x8*)(bp + 2 * gstr);
    bf16x8 b3 = *(const bf16x8*)(bp + 3 * gstr);
    acc[0][0] = __builtin_amdgcn_mfma_f32_16x16x32_bf16(a0, b0, acc[0][0], 0, 0, 0);
    acc[0][1] = __builtin_amdgcn_mfma_f32_16x16x32_bf16(a0, b1, acc[0][1], 0, 0, 0);
    acc[0][2] = __builtin_amdgcn_mfma_f32_16x16x32_bf16(a0, b2, acc[0][2], 0, 0, 0);
    acc[0][3] = __builtin_amdgcn_mfma_f32_16x16x32_bf16(a0, b3, acc[0][3], 0, 0, 0);
    acc[1][0] = __builtin_amdgcn_mfma_f32_16x16x32_bf16(a1, b0, acc[1][0], 0, 0, 0);
    acc[1][1] = __builtin_amdgcn_mfma_f32_16x16x32_bf16(a1, b1, acc[1][1], 0, 0, 0);
    acc[1][2] = __builtin_amdgcn_mfma_f32_16x16x32_bf16(a1, b2, acc[1][2], 0, 0, 0);
    acc[1][3] = __builtin_amdgcn_mfma_f32_16x16x32_bf16(a1, b3, acc[1][3], 0, 0, 0);
  }

  __shared__ float red[4][2][4][4][64];
#pragma unroll
  for (int mt = 0; mt < 2; ++mt)
#pragma unroll
    for (int g = 0; g < 4; ++g)
#pragma unroll
      for (int r = 0; r < 4; ++r) red[wid][mt][g][r][lane] = acc[mt][g][r];
  __syncthreads();
  if (wid != 0) return;

  const int j_h = jt * 16 + lo;
  const float bI = bias[l * 4096 + j_h];
  const float bF = bias[l * 4096 + 1024 + j_h];
  const float bG = bias[l * 4096 + 2048 + j_h];
  const float bO = bias[l * 4096 + 3072 + j_h];
  float* cst = c_state + l * NH;
  bf16* hdst = hbuf + (size_t)l * 2 * NH + (size_t)(t & 1) * NH;

#pragma unroll
  for (int mt = 0; mt < 2; ++mt)
#pragma unroll
    for (int r = 0; r < 4; ++r) {
      const int m = mt * 16 + quad * 4 + r;
      float s0 = 0.f, s1 = 0.f, s2 = 0.f, s3 = 0.f;
#pragma unroll
      for (int w2 = 0; w2 < 4; ++w2) {
        s0 += red[w2][mt][0][r][lane];
        s1 += red[w2][mt][1][r][lane];
        s2 += red[w2][mt][2][r][lane];
        s3 += red[w2][mt][3][r][lane];
      }
      const float ii = sigm(s0 + bI);
      const float ff = sigm(s1 + bF);
      const float gg = tanh_(s2 + bG);
      const float oo = sigm(s3 + bO);
      const int off = m * H_ + j_h;
      const float c = ff * cst[off] + ii * gg;
      cst[off] = c;
      const float h = oo * tanh_(c);
      hdst[off] = (bf16)h;
      if (l == 2) out[(size_t)t * NH + off] = h;
      if (t == T_ - 1) {
        out[32768000 + l * NH + off] = h;
        out[32866304 + l * NH + off] = c;
      }
    }
}

extern "C" void kernel_launch(void* const* d_in, const int* in_sizes, int n_in,
                              void* d_out, int out_size, void* d_ws, size_t ws_size,
                              hipStream_t stream) {
  (void)in_sizes; (void)n_in; (void)out_size;
  const float* x     = (const float*)d_in[0];
  const float* h0    = (const float*)d_in[1];
  const float* c0    = (const float*)d_in[2];
  const float* w_ih0 = (const float*)d_in[3];
  const float* w_ihr = (const float*)d_in[4];
  const float* w_hh  = (const float*)d_in[5];
  const float* b_ih  = (const float*)d_in[6];
  const float* b_hh  = (const float*)d_in[7];
  float* out = (float*)d_out;
  char* ws = (char*)d_ws;

  bf16*     xb      = (bf16*)(ws + 0);
  bf16*     packed  = (bf16*)(ws + 20480000);
  bf16*     hbuf    = (bf16*)(ws + 65044480);
  float*    c_state = (float*)(ws + 65437696);
  float*    bias    = (float*)(ws + 65830912);
  unsigned* slots   = (unsigned*)(ws + 65880064);
  const bool have_slots = ws_size >= 65880064u + 1024u;

  hipLaunchKernelGGL(prep_x, dim3(10000), dim3(256), 0, stream,
                     (const float4*)x, (bf16x4*)xb);
  hipLaunchKernelGGL(prep_pack, dim3(87040), dim3(256), 0, stream,
                     w_ih0, w_ihr, w_hh, packed);
  hipLaunchKernelGGL(prep_state, dim3(384), dim3(256), 0, stream,
                     h0, c0, b_ih, b_hh, hbuf, c_state, bias,
                     have_slots ? slots : (unsigned*)(ws + 65437696));

  const bf16*  xb_c  = (const bf16*)xb;
  const bf16*  pk_c  = (const bf16*)packed;
  bf16*        hb    = hbuf;
  const float* cs_c  = (const float*)c_state;
  const float* bi_c  = (const float*)bias;
  unsigned*    sl    = slots;
  float*       out_p = out;

  hipError_t e = hipErrorUnknown;
  if (have_slots) {
    void* args[7] = {&xb_c, &pk_c, &hb, &cs_c, &bi_c, &sl, &out_p};
    e = hipLaunchCooperativeKernel((const void*)lstm_persist,
                                   dim3(192), dim3(256), args, 0, stream);
  }
  if (e != hipSuccess) {
    (void)hipGetLastError();  // clear error state, fall back to per-wave launches
    for (int wv = 0; wv < T_ + 2; ++wv)
      hipLaunchKernelGGL(lstm_step, dim3(192), dim3(256), 0, stream, wv,
                         xb_c, pk_c, hb, c_state, bias, out);
  }
}

// Round 4
// 10175.388 us; speedup vs baseline: 3.1366x; 1.3231x over previous
//
#include <hip/hip_runtime.h>

// LSTM T=1000 N=32 D=320 H=1024 L=3 on MI355X.
// Persistent cooperative kernel; fence-free grid barrier (slot array + poll with
// s_sleep backoff). h exchange: sc0/sc1 write-through stores + plain pipelined
// sc0/sc1 (L1/L2-bypassing, LLC-coherent) dwordx4 loads, batched 8 per waitcnt.
// Weights RESIDENT on-chip: 8 K-iters/wave in VGPRs + 8 K-iters/wave in LDS.
// c-state + bias in registers; epilogue distributed across all 4 waves.
//
// ws layout (bytes):
//   [0,         20480000)  x as bf16            (T*N*320)
//   [20480000,  65044480)  packed B fragments   (22,282,240 bf16)
//   [65044480,  65437696)  h ping-pong bf16     (L * 2 * N*H)
//   [65437696,  65830912)  c state fp32         (L * N*H)
//   [65830912,  65880064)  bias fp32            (L * 4096)
//   [65880064,  65881088)  barrier slots u32    (192 used, 256 zeroed)

#define T_ 1000
#define N_ 32
#define D_ 320
#define H_ 1024
#define NH (N_ * H_)

typedef __bf16 bf16;
typedef bf16 bf16x8 __attribute__((ext_vector_type(8)));
typedef bf16 bf16x4 __attribute__((ext_vector_type(4)));
typedef float floatx4 __attribute__((ext_vector_type(4)));

__device__ __forceinline__ float sigm(float x) { return 1.f / (1.f + __expf(-x)); }
__device__ __forceinline__ float tanh_(float x) {
  float e = __expf(2.f * x);
  return 1.f - 2.f / (e + 1.f);
}

// 8 pipelined LLC-coherent 16B loads (L1+L2 bypass), one waitcnt. Synchronous
// at asm end -> no async-result hazard.
__device__ __forceinline__ void ld_chunk(const bf16* p00, const bf16* p01,
                                         const bf16* p10, const bf16* p11,
                                         const bf16* p20, const bf16* p21,
                                         const bf16* p30, const bf16* p31,
                                         bf16x8 A0[4], bf16x8 A1[4]) {
  asm volatile(
      "global_load_dwordx4 %0, %8, off sc0 sc1\n\t"
      "global_load_dwordx4 %1, %9, off sc0 sc1\n\t"
      "global_load_dwordx4 %2, %10, off sc0 sc1\n\t"
      "global_load_dwordx4 %3, %11, off sc0 sc1\n\t"
      "global_load_dwordx4 %4, %12, off sc0 sc1\n\t"
      "global_load_dwordx4 %5, %13, off sc0 sc1\n\t"
      "global_load_dwordx4 %6, %14, off sc0 sc1\n\t"
      "global_load_dwordx4 %7, %15, off sc0 sc1\n\t"
      "s_waitcnt vmcnt(0)"
      : "=&v"(A0[0]), "=&v"(A1[0]), "=&v"(A0[1]), "=&v"(A1[1]),
        "=&v"(A0[2]), "=&v"(A1[2]), "=&v"(A0[3]), "=&v"(A1[3])
      : "v"(p00), "v"(p01), "v"(p10), "v"(p11),
        "v"(p20), "v"(p21), "v"(p30), "v"(p31)
      : "memory");
}

// 3 pipelined LLC-coherent 4B loads + waitcnt (barrier poll).
__device__ __forceinline__ void ld_poll3(const unsigned* p0, const unsigned* p1,
                                         const unsigned* p2, unsigned& a,
                                         unsigned& b, unsigned& c) {
  asm volatile(
      "global_load_dword %0, %3, off sc0 sc1\n\t"
      "global_load_dword %1, %4, off sc0 sc1\n\t"
      "global_load_dword %2, %5, off sc0 sc1\n\t"
      "s_waitcnt vmcnt(0)"
      : "=&v"(a), "=&v"(b), "=&v"(c)
      : "v"(p0), "v"(p1), "v"(p2)
      : "memory");
}

// Coherent (LLC write-through) 2B store: bypasses the non-coherent XCD L2.
__device__ __forceinline__ void sth(bf16* p, float h) {
  union { __bf16 b; unsigned short s; } u;
  u.b = (__bf16)h;
  unsigned v = u.s;
  asm volatile("global_store_short %0, %1, off sc0 sc1" :: "v"(p), "v"(v) : "memory");
}

// ---- prep: x (fp32) -> bf16 ----
__global__ __launch_bounds__(256) void prep_x(const float4* __restrict__ x,
                                              bf16x4* __restrict__ xb) {
  int idx = blockIdx.x * 256 + threadIdx.x;  // 2,560,000 threads, 4 elems each
  float4 v = x[idx];
  bf16x4 o;
  o[0] = (bf16)v.x; o[1] = (bf16)v.y; o[2] = (bf16)v.z; o[3] = (bf16)v.w;
  xb[idx] = o;
}

// ---- prep: pack W = [w_ih_l ; w_hh_l] (K x 4096) into MFMA B-fragment order.
__global__ __launch_bounds__(256) void prep_pack(const float* __restrict__ w_ih0,
                                                 const float* __restrict__ w_ihr,
                                                 const float* __restrict__ w_hh,
                                                 bf16* __restrict__ packed) {
  int idx = blockIdx.x * 256 + threadIdx.x;  // 22,282,240 total
  int l, r;
  if (idx < 5505024)       { l = 0; r = idx; }
  else if (idx < 13893632) { l = 1; r = idx - 5505024; }
  else                     { l = 2; r = idx - 13893632; }
  const int i    = r & 7;
  const int lane = (r >> 3) & 63;
  const int q    = r >> 9;
  int kb, p;
  if (l == 0) { kb = q % 42; p = q / 42; }   // KB=42 (10 x-blocks + 32 h-blocks)
  else        { kb = q & 63; p = q >> 6; }   // KB=64 (32 + 32)
  const int jt = p & 63;
  const int g  = p >> 6;
  const int k  = kb * 32 + ((lane >> 4) << 3) + i;
  const int j  = (g << 10) + jt * 16 + (lane & 15);
  const int KX = (l == 0) ? 320 : 1024;
  float v;
  if (k < KX) {
    v = (l == 0) ? w_ih0[(size_t)k * 4096 + j]
                 : w_ihr[(size_t)(l - 1) * 4194304 + (size_t)k * 4096 + j];
  } else {
    v = w_hh[(size_t)l * 4194304 + (size_t)(k - KX) * 4096 + j];
  }
  packed[idx] = (bf16)v;
}

// ---- prep: h0 -> hbuf slot 1, c0 -> c_state, bias sum, zero barrier slots
__global__ __launch_bounds__(256) void prep_state(const float* __restrict__ h0,
                                                  const float* __restrict__ c0,
                                                  const float* __restrict__ b_ih,
                                                  const float* __restrict__ b_hh,
                                                  bf16* __restrict__ hbuf,
                                                  float* __restrict__ c_state,
                                                  float* __restrict__ bias,
                                                  unsigned* __restrict__ slots) {
  int idx = blockIdx.x * 256 + threadIdx.x;  // 98,304 threads
  int l = idx >> 15;                         // NH = 32768
  int rem = idx & 32767;
  hbuf[(size_t)l * 2 * NH + NH + rem] = (bf16)h0[idx];
  c_state[idx] = c0[idx];
  if (idx < 12288) bias[idx] = b_ih[idx] + b_hh[idx];
  if (idx < 256) slots[idx] = 0u;
}

// ======================= persistent cooperative kernel =======================
// grid = 192 blocks (3 layers x 64 j-tiles), 256 threads (4 waves, K-split).
// 1 block/CU. Loop wv = 0..1001; fence-free slot barrier with s_sleep backoff.
__global__ __launch_bounds__(256, 1) void lstm_persist(
    const bf16* __restrict__ xb, const bf16* __restrict__ packed,
    bf16* hbuf,                     // read AND written (no restrict)
    const float* __restrict__ c_state, const float* __restrict__ bias,
    unsigned* slots,
    float* __restrict__ out) {
  const int l  = blockIdx.x >> 6;
  const int jt = blockIdx.x & 63;
  const int tid  = threadIdx.x;
  const int wid  = __builtin_amdgcn_readfirstlane(tid >> 6);  // wave-uniform -> SGPR
  const int lane = tid & 63;
  const int quad = lane >> 4;
  const int lo   = lane & 15;

  const int KB   = (l == 0) ? 42 : 64;
  const int KXb  = (l == 0) ? 10 : 32;
  const int xstr = (l == 0) ? D_ : H_;
  const size_t lbase = (l == 0) ? 0 : (l == 1 ? 5505024u : 13893632u);
  const int gstr = 64 * KB * 512;                 // per-gate stride (elements)
  const bf16* Bb = packed + lbase + (size_t)jt * KB * 512;

  // LDS: weight slice for K-iters n=8..15 (per wave) + cross-wave reduce buffer
  // (3 of 4 rows per wave; each wave keeps its own row r==wid in registers).
  __shared__ bf16x8 wlds[4][8][4][64];            // [wid][n-8][g][lane]  128 KiB
  __shared__ float  red[4][2][4][3][64];          // [wid][mt][g][ri][lane] 24 KiB

  // ---- one-time: weights -> VGPRs (n<8) and LDS (n>=8). Own-wave slice only.
  bf16x8 wreg[8][4];
#pragma unroll
  for (int n = 0; n < 8; ++n) {
    const int kb = wid + 4 * n;
    const bf16* bp = Bb + kb * 512 + lane * 8;
#pragma unroll
    for (int g = 0; g < 4; ++g)
      wreg[n][g] = *(const bf16x8*)(bp + (size_t)g * gstr);
  }
  for (int n = 8; wid + 4 * n < KB; ++n) {
    const int kb = wid + 4 * n;
    const bf16* bp = Bb + kb * 512 + lane * 8;
#pragma unroll
    for (int g = 0; g < 4; ++g)
      wlds[wid][n - 8][g][lane] = *(const bf16x8*)(bp + (size_t)g * gstr);
  }

  // ---- one-time: bias + c into registers. This wave owns rows r = wid.
  const int j_h = jt * 16 + lo;
  const float bI = bias[l * 4096 + j_h];
  const float bF = bias[l * 4096 + 1024 + j_h];
  const float bG = bias[l * 4096 + 2048 + j_h];
  const float bO = bias[l * 4096 + 3072 + j_h];
  float creg[2];
#pragma unroll
  for (int mt = 0; mt < 2; ++mt)
    creg[mt] = c_state[l * NH + (mt * 16 + quad * 4 + wid) * H_ + j_h];

  const int arow0 = lo * xstr + quad * 8;
  const int arow1 = (16 + lo) * xstr + quad * 8;
  const int hrow0 = lo * H_ + quad * 8;
  const int hrow1 = (16 + lo) * H_ + quad * 8;

  for (int wv = 0; wv < T_ + 2; ++wv) {
    const int t = wv - l;
    if (t >= 0 && t < T_) {                       // block-uniform predicate
      const bf16* xsrc = (l == 0)
          ? (xb + (size_t)t * (N_ * D_))
          : (hbuf + (size_t)(l - 1) * 2 * NH + (size_t)(t & 1) * NH);
      const bf16* hsrc = hbuf + (size_t)l * 2 * NH + (size_t)((t - 1) & 1) * NH;

      floatx4 acc[2][4];
      const floatx4 zero = {0.f, 0.f, 0.f, 0.f};
#pragma unroll
      for (int mt = 0; mt < 2; ++mt)
#pragma unroll
        for (int g = 0; g < 4; ++g) acc[mt][g] = zero;

      // K-loop: 4 chunks of 4 iters; 8 pipelined LLC loads then 32 MFMA.
#pragma unroll
      for (int ch = 0; ch < 4; ++ch) {
        const int n0 = 4 * ch;
        if (wid + 4 * n0 < KB) {                  // wave-uniform (l0 skips ch 3)
          const bf16* P0[4];
          const bf16* P1[4];
#pragma unroll
          for (int u = 0; u < 4; ++u) {
            const int n = n0 + u;
            const int kb = wid + 4 * n;
            const bf16* p;
            int r0, r1;
            if (kb < KXb)     { p = xsrc + kb * 32;         r0 = arow0; r1 = arow1; }
            else if (kb < KB) { p = hsrc + (kb - KXb) * 32; r0 = hrow0; r1 = hrow1; }
            else              { p = hsrc;                   r0 = 0;     r1 = 0;     } // safe dummy
            P0[u] = p + r0;
            P1[u] = p + r1;
          }
          bf16x8 A0[4], A1[4];
          ld_chunk(P0[0], P1[0], P0[1], P1[1], P0[2], P1[2], P0[3], P1[3], A0, A1);
#pragma unroll
          for (int u = 0; u < 4; ++u) {
            const int n = n0 + u;
            const int kb = wid + 4 * n;
            if (kb < KB) {
              bf16x8 b0, b1, b2, b3;
              if (n < 8) {                         // static n: stays in VGPRs
                b0 = wreg[n][0]; b1 = wreg[n][1]; b2 = wreg[n][2]; b3 = wreg[n][3];
              } else {
                b0 = wlds[wid][n - 8][0][lane];
                b1 = wlds[wid][n - 8][1][lane];
                b2 = wlds[wid][n - 8][2][lane];
                b3 = wlds[wid][n - 8][3][lane];
              }
              acc[0][0] = __builtin_amdgcn_mfma_f32_16x16x32_bf16(A0[u], b0, acc[0][0], 0, 0, 0);
              acc[0][1] = __builtin_amdgcn_mfma_f32_16x16x32_bf16(A0[u], b1, acc[0][1], 0, 0, 0);
              acc[0][2] = __builtin_amdgcn_mfma_f32_16x16x32_bf16(A0[u], b2, acc[0][2], 0, 0, 0);
              acc[0][3] = __builtin_amdgcn_mfma_f32_16x16x32_bf16(A0[u], b3, acc[0][3], 0, 0, 0);
              acc[1][0] = __builtin_amdgcn_mfma_f32_16x16x32_bf16(A1[u], b0, acc[1][0], 0, 0, 0);
              acc[1][1] = __builtin_amdgcn_mfma_f32_16x16x32_bf16(A1[u], b1, acc[1][1], 0, 0, 0);
              acc[1][2] = __builtin_amdgcn_mfma_f32_16x16x32_bf16(A1[u], b2, acc[1][2], 0, 0, 0);
              acc[1][3] = __builtin_amdgcn_mfma_f32_16x16x32_bf16(A1[u], b3, acc[1][3], 0, 0, 0);
            }
          }
        }
      }

      // publish partial sums for rows this wave does NOT own (r != wid)
#pragma unroll
      for (int mt = 0; mt < 2; ++mt)
#pragma unroll
        for (int g = 0; g < 4; ++g)
#pragma unroll
          for (int r = 0; r < 4; ++r)
            if (r != wid) red[wid][mt][g][r - (r > wid ? 1 : 0)][lane] = acc[mt][g][r];
      __syncthreads();

      // distributed epilogue: wave `wid` handles rows r = wid (both mt).
      bf16* hdst = hbuf + (size_t)l * 2 * NH + (size_t)(t & 1) * NH;
#pragma unroll
      for (int mt = 0; mt < 2; ++mt) {
        float s[4];
#pragma unroll
        for (int g = 0; g < 4; ++g) {
          float sum = (wid == 0) ? acc[mt][g][0]
                    : (wid == 1) ? acc[mt][g][1]
                    : (wid == 2) ? acc[mt][g][2] : acc[mt][g][3];
#pragma unroll
          for (int w2 = 0; w2 < 4; ++w2)
            if (w2 != wid)
              sum += red[w2][mt][g][wid - (wid > w2 ? 1 : 0)][lane];
          s[g] = sum;
        }
        const float ii = sigm(s[0] + bI);
        const float ff = sigm(s[1] + bF);
        const float gg = tanh_(s[2] + bG);
        const float oo = sigm(s[3] + bO);
        const float c = ff * creg[mt] + ii * gg;
        creg[mt] = c;
        const float h = oo * tanh_(c);
        const int off = (mt * 16 + quad * 4 + wid) * H_ + j_h;
        sth(hdst + off, h);                       // sc0 sc1 write-through to LLC
        if (l == 2) __builtin_nontemporal_store(h, &out[(size_t)t * NH + off]);
        if (t == T_ - 1) {
          __builtin_nontemporal_store(h, &out[32768000 + l * NH + off]);  // hT
          __builtin_nontemporal_store(c, &out[32866304 + l * NH + off]);  // cT
        }
      }
    }

    // ---- fence-free grid barrier. __syncthreads drains vmcnt(0) per wave,
    // so all sc1 h-stores are in the LLC before the slot publish.
    __syncthreads();
    if (wid == 0) {
      __hip_atomic_store(&slots[blockIdx.x], (unsigned)(wv + 1),
                         __ATOMIC_RELAXED, __HIP_MEMORY_SCOPE_AGENT);
      const unsigned tgt = (unsigned)(wv + 1);
      for (;;) {
        unsigned a, b, c;
        ld_poll3(&slots[lane], &slots[lane + 64], &slots[lane + 128], a, b, c);
        if (__all((a >= tgt) && (b >= tgt) && (c >= tgt))) break;
        __builtin_amdgcn_s_sleep(2);              // ~128 cyc backoff
      }
    }
    __syncthreads();
  }
}

// ======================= fallback: launch-per-wave step =======================
__global__ __launch_bounds__(256) void lstm_step(int wv,
                                                 const bf16* __restrict__ xb,
                                                 const bf16* __restrict__ packed,
                                                 bf16* __restrict__ hbuf,
                                                 float* __restrict__ c_state,
                                                 const float* __restrict__ bias,
                                                 float* __restrict__ out) {
  const int l  = blockIdx.x >> 6;
  const int jt = blockIdx.x & 63;
  const int t  = wv - l;
  if (t < 0 || t >= T_) return;

  const int tid  = threadIdx.x;
  const int wid  = tid >> 6;
  const int lane = tid & 63;
  const int quad = lane >> 4;
  const int lo   = lane & 15;

  const int KB   = (l == 0) ? 42 : 64;
  const int KXb  = (l == 0) ? 10 : 32;
  const int xstr = (l == 0) ? D_ : H_;
  const bf16* xsrc = (l == 0) ? (xb + (size_t)t * (N_ * D_))
                              : (hbuf + (size_t)(l - 1) * 2 * NH + (size_t)(t & 1) * NH);
  const bf16* hsrc = hbuf + (size_t)l * 2 * NH + (size_t)((t - 1) & 1) * NH;
  const size_t lbase = (l == 0) ? 0 : (l == 1 ? 5505024u : 13893632u);
  const int gstr = 64 * KB * 512;
  const bf16* Bb = packed + lbase + (size_t)jt * KB * 512;

  floatx4 acc[2][4];
  const floatx4 zero = {0.f, 0.f, 0.f, 0.f};
#pragma unroll
  for (int mt = 0; mt < 2; ++mt)
#pragma unroll
    for (int g = 0; g < 4; ++g) acc[mt][g] = zero;

  const int arow0 = lo * xstr + quad * 8;
  const int arow1 = (16 + lo) * xstr + quad * 8;
  const int hrow0 = lo * H_ + quad * 8;
  const int hrow1 = (16 + lo) * H_ + quad * 8;

#pragma unroll 2
  for (int kb = wid; kb < KB; kb += 4) {
    bf16x8 a0, a1;
    if (kb < KXb) {
      const bf16* p = xsrc + kb * 32;
      a0 = *(const bf16x8*)(p + arow0);
      a1 = *(const bf16x8*)(p + arow1);
    } else {
      const bf16* p = hsrc + (kb - KXb) * 32;
      a0 = *(const bf16x8*)(p + hrow0);
      a1 = *(const bf16x8*)(p + hrow1);
    }
    const bf16* bp = Bb + kb * 512 + lane * 8;
    bf16x8 b0 = *(const bf16x8*)(bp);
    bf16x8 b1 = *(const bf16x8*)(bp + gstr);
    bf16x8 b2 = *(const bf16x8*)(bp + 2 * gstr);
    bf16x8 b3 = *(const bf16x8*)(bp + 3 * gstr);
    acc[0][0] = __builtin_amdgcn_mfma_f32_16x16x32_bf16(a0, b0, acc[0][0], 0, 0, 0);
    acc[0][1] = __builtin_amdgcn_mfma_f32_16x16x32_bf16(a0, b1, acc[0][1], 0, 0, 0);
    acc[0][2] = __builtin_amdgcn_mfma_f32_16x16x32_bf16(a0, b2, acc[0][2], 0, 0, 0);
    acc[0][3] = __builtin_amdgcn_mfma_f32_16x16x32_bf16(a0, b3, acc[0][3], 0, 0, 0);
    acc[1][0] = __builtin_amdgcn_mfma_f32_16x16x32_bf16(a1, b0, acc[1][0], 0, 0, 0);
    acc[1][1] = __builtin_amdgcn_mfma_f32_16x16x32_bf16(a1, b1, acc[1][1], 0, 0, 0);
    acc[1][2] = __builtin_amdgcn_mfma_f32_16x16x32_bf16(a1, b2, acc[1][2], 0, 0, 0);
    acc[1][3] = __builtin_amdgcn_mfma_f32_16x16x32_bf16(a1, b3, acc[1][3], 0, 0, 0);
  }

  __shared__ float red[4][2][4][4][64];
#pragma unroll
  for (int mt = 0; mt < 2; ++mt)
#pragma unroll
    for (int g = 0; g < 4; ++g)
#pragma unroll
      for (int r = 0; r < 4; ++r) red[wid][mt][g][r][lane] = acc[mt][g][r];
  __syncthreads();
  if (wid != 0) return;

  const int j_h = jt * 16 + lo;
  const float bI = bias[l * 4096 + j_h];
  const float bF = bias[l * 4096 + 1024 + j_h];
  const float bG = bias[l * 4096 + 2048 + j_h];
  const float bO = bias[l * 4096 + 3072 + j_h];
  float* cst = c_state + l * NH;
  bf16* hdst = hbuf + (size_t)l * 2 * NH + (size_t)(t & 1) * NH;

#pragma unroll
  for (int mt = 0; mt < 2; ++mt)
#pragma unroll
    for (int r = 0; r < 4; ++r) {
      const int m = mt * 16 + quad * 4 + r;
      float s0 = 0.f, s1 = 0.f, s2 = 0.f, s3 = 0.f;
#pragma unroll
      for (int w2 = 0; w2 < 4; ++w2) {
        s0 += red[w2][mt][0][r][lane];
        s1 += red[w2][mt][1][r][lane];
        s2 += red[w2][mt][2][r][lane];
        s3 += red[w2][mt][3][r][lane];
      }
      const float ii = sigm(s0 + bI);
      const float ff = sigm(s1 + bF);
      const float gg = tanh_(s2 + bG);
      const float oo = sigm(s3 + bO);
      const int off = m * H_ + j_h;
      const float c = ff * cst[off] + ii * gg;
      cst[off] = c;
      const float h = oo * tanh_(c);
      hdst[off] = (bf16)h;
      if (l == 2) out[(size_t)t * NH + off] = h;
      if (t == T_ - 1) {
        out[32768000 + l * NH + off] = h;
        out[32866304 + l * NH + off] = c;
      }
    }
}

extern "C" void kernel_launch(void* const* d_in, const int* in_sizes, int n_in,
                              void* d_out, int out_size, void* d_ws, size_t ws_size,
                              hipStream_t stream) {
  (void)in_sizes; (void)n_in; (void)out_size;
  const float* x     = (const float*)d_in[0];
  const float* h0    = (const float*)d_in[1];
  const float* c0    = (const float*)d_in[2];
  const float* w_ih0 = (const float*)d_in[3];
  const float* w_ihr = (const float*)d_in[4];
  const float* w_hh  = (const float*)d_in[5];
  const float* b_ih  = (const float*)d_in[6];
  const float* b_hh  = (const float*)d_in[7];
  float* out = (float*)d_out;
  char* ws = (char*)d_ws;

  bf16*     xb      = (bf16*)(ws + 0);
  bf16*     packed  = (bf16*)(ws + 20480000);
  bf16*     hbuf    = (bf16*)(ws + 65044480);
  float*    c_state = (float*)(ws + 65437696);
  float*    bias    = (float*)(ws + 65830912);
  unsigned* slots   = (unsigned*)(ws + 65880064);
  const bool have_slots = ws_size >= 65880064u + 1024u;

  hipLaunchKernelGGL(prep_x, dim3(10000), dim3(256), 0, stream,
                     (const float4*)x, (bf16x4*)xb);
  hipLaunchKernelGGL(prep_pack, dim3(87040), dim3(256), 0, stream,
                     w_ih0, w_ihr, w_hh, packed);
  hipLaunchKernelGGL(prep_state, dim3(384), dim3(256), 0, stream,
                     h0, c0, b_ih, b_hh, hbuf, c_state, bias,
                     have_slots ? slots : (unsigned*)(ws + 65437696));

  const bf16*  xb_c  = (const bf16*)xb;
  const bf16*  pk_c  = (const bf16*)packed;
  bf16*        hb    = hbuf;
  const float* cs_c  = (const float*)c_state;
  const float* bi_c  = (const float*)bias;
  unsigned*    sl    = slots;
  float*       out_p = out;

  hipError_t e = hipErrorUnknown;
  if (have_slots) {
    void* args[7] = {&xb_c, &pk_c, &hb, &cs_c, &bi_c, &sl, &out_p};
    e = hipLaunchCooperativeKernel((const void*)lstm_persist,
                                   dim3(192), dim3(256), args, 0, stream);
  }
  if (e != hipSuccess) {
    (void)hipGetLastError();  // clear error state, fall back to per-wave launches
    for (int wv = 0; wv < T_ + 2; ++wv)
      hipLaunchKernelGGL(lstm_step, dim3(192), dim3(256), 0, stream, wv,
                         xb_c, pk_c, hb, c_state, bias, out);
  }
}

// Round 8
// 10159.999 us; speedup vs baseline: 3.1413x; 1.0015x over previous
//
#include <hip/hip_runtime.h>

// LSTM T=1000 N=32 D=320 H=1024 L=3 on MI355X.
// Persistent cooperative kernel; fence-free grid barrier (R4-proven structure:
// pre-publish __syncthreads, wave-0 poll with s_sleep backoff, trailing
// __syncthreads). h exchange: sc0/sc1 write-through stores + plain sc0/sc1
// LLC-coherent loads. A-loads: 2-chunk-ahead pipeline (<=16 loads in flight,
// <=64 A-VGPRs live -> no spills -> exact vmcnt counts; R5's 32-deep burst
// overflowed the 256-VGPR file -> scratch VMEM corrupted the counts).
// Weights RESIDENT on-chip: 8 K-iters/wave in VGPRs + 8 K-iters/wave in LDS.
// c-state + bias in registers; epilogue distributed across all 4 waves.
// [R8 = identical resubmit of R7: R6/R7 errors were infra-level (no timing
//  dict, no pytest output -> container died before kernel execution).]
//
// ws layout (bytes):
//   [0,         20480000)  x as bf16            (T*N*320)
//   [20480000,  65044480)  packed B fragments   (22,282,240 bf16)
//   [65044480,  65437696)  h ping-pong bf16     (L * 2 * N*H)
//   [65437696,  65830912)  c state fp32         (L * N*H)
//   [65830912,  65880064)  bias fp32            (L * 4096)
//   [65880064,  65881088)  barrier slots u32    (192 used, 256 zeroed)

#define T_ 1000
#define N_ 32
#define D_ 320
#define H_ 1024
#define NH (N_ * H_)

typedef __bf16 bf16;
typedef bf16 bf16x8 __attribute__((ext_vector_type(8)));
typedef bf16 bf16x4 __attribute__((ext_vector_type(4)));
typedef float floatx4 __attribute__((ext_vector_type(4)));

__device__ __forceinline__ float sigm(float x) { return 1.f / (1.f + __expf(-x)); }
__device__ __forceinline__ float tanh_(float x) {
  float e = __expf(2.f * x);
  return 1.f - 2.f / (e + 1.f);
}

// Issue 8 LLC-coherent 16B loads (L1+L2 bypass), NO waitcnt — caller waits
// with a counted vmcnt tied to the outputs.
__device__ __forceinline__ void ld8_issue(const bf16* p00, const bf16* p01,
                                          const bf16* p10, const bf16* p11,
                                          const bf16* p20, const bf16* p21,
                                          const bf16* p30, const bf16* p31,
                                          bf16x8 A0[4], bf16x8 A1[4]) {
  asm volatile(
      "global_load_dwordx4 %0, %8, off sc0 sc1\n\t"
      "global_load_dwordx4 %1, %9, off sc0 sc1\n\t"
      "global_load_dwordx4 %2, %10, off sc0 sc1\n\t"
      "global_load_dwordx4 %3, %11, off sc0 sc1\n\t"
      "global_load_dwordx4 %4, %12, off sc0 sc1\n\t"
      "global_load_dwordx4 %5, %13, off sc0 sc1\n\t"
      "global_load_dwordx4 %6, %14, off sc0 sc1\n\t"
      "global_load_dwordx4 %7, %15, off sc0 sc1"
      : "=&v"(A0[0]), "=&v"(A1[0]), "=&v"(A0[1]), "=&v"(A1[1]),
        "=&v"(A0[2]), "=&v"(A1[2]), "=&v"(A0[3]), "=&v"(A1[3])
      : "v"(p00), "v"(p01), "v"(p10), "v"(p11),
        "v"(p20), "v"(p21), "v"(p30), "v"(p31)
      : "memory");
}

// Counted wait tied to the chunk's result registers, then a scheduling fence
// so no consumer is hoisted above the wait (guide rule 18).
#define TIE_WAIT(NSTR, Ax, Ay)                                              \
  do {                                                                      \
    asm volatile("s_waitcnt vmcnt(" NSTR ")"                                \
                 : "+v"(Ax[0]), "+v"(Ax[1]), "+v"(Ax[2]), "+v"(Ax[3]),      \
                   "+v"(Ay[0]), "+v"(Ay[1]), "+v"(Ay[2]), "+v"(Ay[3])       \
                 :: "memory");                                              \
    __builtin_amdgcn_sched_barrier(0);                                      \
  } while (0)

// 3 pipelined LLC-coherent 4B loads + waitcnt (barrier poll).
__device__ __forceinline__ void ld_poll3(const unsigned* p0, const unsigned* p1,
                                         const unsigned* p2, unsigned& a,
                                         unsigned& b, unsigned& c) {
  asm volatile(
      "global_load_dword %0, %3, off sc0 sc1\n\t"
      "global_load_dword %1, %4, off sc0 sc1\n\t"
      "global_load_dword %2, %5, off sc0 sc1\n\t"
      "s_waitcnt vmcnt(0)"
      : "=&v"(a), "=&v"(b), "=&v"(c)
      : "v"(p0), "v"(p1), "v"(p2)
      : "memory");
}

// Coherent (LLC write-through) 2B store: bypasses the non-coherent XCD L2.
__device__ __forceinline__ void sth(bf16* p, float h) {
  union { __bf16 b; unsigned short s; } u;
  u.b = (__bf16)h;
  unsigned v = u.s;
  asm volatile("global_store_short %0, %1, off sc0 sc1" :: "v"(p), "v"(v) : "memory");
}

// ---- prep: x (fp32) -> bf16 ----
__global__ __launch_bounds__(256) void prep_x(const float4* __restrict__ x,
                                              bf16x4* __restrict__ xb) {
  int idx = blockIdx.x * 256 + threadIdx.x;  // 2,560,000 threads, 4 elems each
  float4 v = x[idx];
  bf16x4 o;
  o[0] = (bf16)v.x; o[1] = (bf16)v.y; o[2] = (bf16)v.z; o[3] = (bf16)v.w;
  xb[idx] = o;
}

// ---- prep: pack W = [w_ih_l ; w_hh_l] (K x 4096) into MFMA B-fragment order.
__global__ __launch_bounds__(256) void prep_pack(const float* __restrict__ w_ih0,
                                                 const float* __restrict__ w_ihr,
                                                 const float* __restrict__ w_hh,
                                                 bf16* __restrict__ packed) {
  int idx = blockIdx.x * 256 + threadIdx.x;  // 22,282,240 total
  int l, r;
  if (idx < 5505024)       { l = 0; r = idx; }
  else if (idx < 13893632) { l = 1; r = idx - 5505024; }
  else                     { l = 2; r = idx - 13893632; }
  const int i    = r & 7;
  const int lane = (r >> 3) & 63;
  const int q    = r >> 9;
  int kb, p;
  if (l == 0) { kb = q % 42; p = q / 42; }   // KB=42 (10 x-blocks + 32 h-blocks)
  else        { kb = q & 63; p = q >> 6; }   // KB=64 (32 + 32)
  const int jt = p & 63;
  const int g  = p >> 6;
  const int k  = kb * 32 + ((lane >> 4) << 3) + i;
  const int j  = (g << 10) + jt * 16 + (lane & 15);
  const int KX = (l == 0) ? 320 : 1024;
  float v;
  if (k < KX) {
    v = (l == 0) ? w_ih0[(size_t)k * 4096 + j]
                 : w_ihr[(size_t)(l - 1) * 4194304 + (size_t)k * 4096 + j];
  } else {
    v = w_hh[(size_t)l * 4194304 + (size_t)(k - KX) * 4096 + j];
  }
  packed[idx] = (bf16)v;
}

// ---- prep: h0 -> hbuf slot 1, c0 -> c_state, bias sum, zero barrier slots
__global__ __launch_bounds__(256) void prep_state(const float* __restrict__ h0,
                                                  const float* __restrict__ c0,
                                                  const float* __restrict__ b_ih,
                                                  const float* __restrict__ b_hh,
                                                  bf16* __restrict__ hbuf,
                                                  float* __restrict__ c_state,
                                                  float* __restrict__ bias,
                                                  unsigned* __restrict__ slots) {
  int idx = blockIdx.x * 256 + threadIdx.x;  // 98,304 threads
  int l = idx >> 15;                         // NH = 32768
  int rem = idx & 32767;
  hbuf[(size_t)l * 2 * NH + NH + rem] = (bf16)h0[idx];
  c_state[idx] = c0[idx];
  if (idx < 12288) bias[idx] = b_ih[idx] + b_hh[idx];
  if (idx < 256) slots[idx] = 0u;
}

// ======================= persistent cooperative kernel =======================
// grid = 192 blocks (3 layers x 64 j-tiles), 256 threads (4 waves, K-split).
// 1 block/CU. Loop wv = 0..1001; fence-free slot barrier (R4 structure).
__global__ __launch_bounds__(256, 1) void lstm_persist(
    const bf16* __restrict__ xb, const bf16* __restrict__ packed,
    bf16* hbuf,                     // read AND written (no restrict)
    const float* __restrict__ c_state, const float* __restrict__ bias,
    unsigned* slots,
    float* __restrict__ out) {
  const int l  = blockIdx.x >> 6;
  const int jt = blockIdx.x & 63;
  const int tid  = threadIdx.x;
  const int wid  = __builtin_amdgcn_readfirstlane(tid >> 6);  // wave-uniform -> SGPR
  const int lane = tid & 63;
  const int quad = lane >> 4;
  const int lo   = lane & 15;

  const int KB   = (l == 0) ? 42 : 64;
  const int KXb  = (l == 0) ? 10 : 32;
  const int xstr = (l == 0) ? D_ : H_;
  const size_t lbase = (l == 0) ? 0 : (l == 1 ? 5505024u : 13893632u);
  const int gstr = 64 * KB * 512;                 // per-gate stride (elements)
  const bf16* Bb = packed + lbase + (size_t)jt * KB * 512;

  // LDS: weight slice for K-iters n=8..15 (per wave) + cross-wave reduce buffer
  // (3 of 4 rows per wave; each wave keeps its own row r==wid in registers).
  __shared__ bf16x8 wlds[4][8][4][64];            // [wid][n-8][g][lane]  128 KiB
  __shared__ float  red[4][2][4][3][64];          // [wid][mt][g][ri][lane] 24 KiB

  // ---- one-time: weights -> VGPRs (n<8) and LDS (n>=8). Own-wave slice only.
  bf16x8 wreg[8][4];
#pragma unroll
  for (int n = 0; n < 8; ++n) {
    const int kb = wid + 4 * n;
    const bf16* bp = Bb + kb * 512 + lane * 8;
#pragma unroll
    for (int g = 0; g < 4; ++g)
      wreg[n][g] = *(const bf16x8*)(bp + (size_t)g * gstr);
  }
  for (int n = 8; wid + 4 * n < KB; ++n) {
    const int kb = wid + 4 * n;
    const bf16* bp = Bb + kb * 512 + lane * 8;
#pragma unroll
    for (int g = 0; g < 4; ++g)
      wlds[wid][n - 8][g][lane] = *(const bf16x8*)(bp + (size_t)g * gstr);
  }

  // ---- one-time: bias + c into registers. This wave owns rows r = wid.
  const int j_h = jt * 16 + lo;
  const float bI = bias[l * 4096 + j_h];
  const float bF = bias[l * 4096 + 1024 + j_h];
  const float bG = bias[l * 4096 + 2048 + j_h];
  const float bO = bias[l * 4096 + 3072 + j_h];
  float creg[2];
#pragma unroll
  for (int mt = 0; mt < 2; ++mt)
    creg[mt] = c_state[l * NH + (mt * 16 + quad * 4 + wid) * H_ + j_h];

  const int arow0 = lo * xstr + quad * 8;
  const int arow1 = (16 + lo) * xstr + quad * 8;
  const int hrow0 = lo * H_ + quad * 8;
  const int hrow1 = (16 + lo) * H_ + quad * 8;

// issue chunk CH's 8 loads (no wait)
#define ISSUE_CHUNK(CH)                                                          \
  do {                                                                           \
    const bf16 *P0[4], *P1[4];                                                   \
    _Pragma("unroll")                                                            \
    for (int u = 0; u < 4; ++u) {                                                \
      const int kb = wid + 4 * (4 * (CH) + u);                                   \
      const bf16* p;                                                             \
      int r0, r1;                                                                \
      if (kb < KXb)     { p = xsrc + kb * 32;         r0 = arow0; r1 = arow1; }  \
      else if (kb < KB) { p = hsrc + (kb - KXb) * 32; r0 = hrow0; r1 = hrow1; }  \
      else              { p = hsrc;                   r0 = 0;     r1 = 0;     }  \
      P0[u] = p + r0;                                                            \
      P1[u] = p + r1;                                                            \
    }                                                                            \
    ld8_issue(P0[0], P1[0], P0[1], P1[1], P0[2], P1[2], P0[3], P1[3],            \
              A0[CH], A1[CH]);                                                   \
  } while (0)

// one chunk's 8 MFMA x 4 sub-iters (n = 4*CH + u); u unrolled -> static wreg idx
#define CONSUME_CHUNK(CH)                                                        \
  _Pragma("unroll")                                                              \
  for (int u = 0; u < 4; ++u) {                                                  \
    const int n = 4 * (CH) + u;                                                  \
    const int kb = wid + 4 * n;                                                  \
    if (kb < KB) {                                                               \
      bf16x8 b0, b1, b2, b3;                                                     \
      if (n < 8) {                                                               \
        b0 = wreg[n][0]; b1 = wreg[n][1]; b2 = wreg[n][2]; b3 = wreg[n][3];      \
      } else {                                                                   \
        b0 = wlds[wid][n - 8][0][lane];                                          \
        b1 = wlds[wid][n - 8][1][lane];                                          \
        b2 = wlds[wid][n - 8][2][lane];                                          \
        b3 = wlds[wid][n - 8][3][lane];                                          \
      }                                                                          \
      acc[0][0] = __builtin_amdgcn_mfma_f32_16x16x32_bf16(A0[CH][u], b0, acc[0][0], 0, 0, 0); \
      acc[0][1] = __builtin_amdgcn_mfma_f32_16x16x32_bf16(A0[CH][u], b1, acc[0][1], 0, 0, 0); \
      acc[0][2] = __builtin_amdgcn_mfma_f32_16x16x32_bf16(A0[CH][u], b2, acc[0][2], 0, 0, 0); \
      acc[0][3] = __builtin_amdgcn_mfma_f32_16x16x32_bf16(A0[CH][u], b3, acc[0][3], 0, 0, 0); \
      acc[1][0] = __builtin_amdgcn_mfma_f32_16x16x32_bf16(A1[CH][u], b0, acc[1][0], 0, 0, 0); \
      acc[1][1] = __builtin_amdgcn_mfma_f32_16x16x32_bf16(A1[CH][u], b1, acc[1][1], 0, 0, 0); \
      acc[1][2] = __builtin_amdgcn_mfma_f32_16x16x32_bf16(A1[CH][u], b2, acc[1][2], 0, 0, 0); \
      acc[1][3] = __builtin_amdgcn_mfma_f32_16x16x32_bf16(A1[CH][u], b3, acc[1][3], 0, 0, 0); \
    }                                                                            \
  }

  for (int wv = 0; wv < T_ + 2; ++wv) {
    const int t = wv - l;
    if (t >= 0 && t < T_) {                       // block-uniform predicate
      const bf16* xsrc = (l == 0)
          ? (xb + (size_t)t * (N_ * D_))
          : (hbuf + (size_t)(l - 1) * 2 * NH + (size_t)(t & 1) * NH);
      const bf16* hsrc = hbuf + (size_t)l * 2 * NH + (size_t)((t - 1) & 1) * NH;

      floatx4 acc[2][4];
      const floatx4 zero = {0.f, 0.f, 0.f, 0.f};
#pragma unroll
      for (int mt = 0; mt < 2; ++mt)
#pragma unroll
        for (int g = 0; g < 4; ++g) acc[mt][g] = zero;

      // ---- 2-chunk-ahead pipeline: <=16 loads in flight, exact vmcnt counts.
      bf16x8 A0[4][4], A1[4][4];
      if (l == 0) {                               // 3 chunks (KB=42)
        ISSUE_CHUNK(0); ISSUE_CHUNK(1);
        TIE_WAIT("8", A0[0], A1[0]); CONSUME_CHUNK(0); ISSUE_CHUNK(2);
        TIE_WAIT("8", A0[1], A1[1]); CONSUME_CHUNK(1);
        TIE_WAIT("0", A0[2], A1[2]); CONSUME_CHUNK(2);
      } else {                                    // 4 chunks (KB=64)
        ISSUE_CHUNK(0); ISSUE_CHUNK(1);
        TIE_WAIT("8", A0[0], A1[0]); CONSUME_CHUNK(0); ISSUE_CHUNK(2);
        TIE_WAIT("8", A0[1], A1[1]); CONSUME_CHUNK(1); ISSUE_CHUNK(3);
        TIE_WAIT("8", A0[2], A1[2]); CONSUME_CHUNK(2);
        TIE_WAIT("0", A0[3], A1[3]); CONSUME_CHUNK(3);
      }

      // publish partial sums for rows this wave does NOT own (r != wid)
#pragma unroll
      for (int mt = 0; mt < 2; ++mt)
#pragma unroll
        for (int g = 0; g < 4; ++g)
#pragma unroll
          for (int r = 0; r < 4; ++r)
            if (r != wid) red[wid][mt][g][r - (r > wid ? 1 : 0)][lane] = acc[mt][g][r];
      __syncthreads();

      // distributed epilogue: wave `wid` handles rows r = wid (both mt).
      bf16* hdst = hbuf + (size_t)l * 2 * NH + (size_t)(t & 1) * NH;
#pragma unroll
      for (int mt = 0; mt < 2; ++mt) {
        float s[4];
#pragma unroll
        for (int g = 0; g < 4; ++g) {
          float sum = (wid == 0) ? acc[mt][g][0]
                    : (wid == 1) ? acc[mt][g][1]
                    : (wid == 2) ? acc[mt][g][2] : acc[mt][g][3];
#pragma unroll
          for (int w2 = 0; w2 < 4; ++w2)
            if (w2 != wid)
              sum += red[w2][mt][g][wid - (wid > w2 ? 1 : 0)][lane];
          s[g] = sum;
        }
        const float ii = sigm(s[0] + bI);
        const float ff = sigm(s[1] + bF);
        const float gg = tanh_(s[2] + bG);
        const float oo = sigm(s[3] + bO);
        const float c = ff * creg[mt] + ii * gg;
        creg[mt] = c;
        const float h = oo * tanh_(c);
        const int off = (mt * 16 + quad * 4 + wid) * H_ + j_h;
        sth(hdst + off, h);                       // sc0 sc1 write-through to LLC
        if (l == 2) __builtin_nontemporal_store(h, &out[(size_t)t * NH + off]);
        if (t == T_ - 1) {
          __builtin_nontemporal_store(h, &out[32768000 + l * NH + off]);  // hT
          __builtin_nontemporal_store(c, &out[32866304 + l * NH + off]);  // cT
        }
      }
    }

    // ---- fence-free grid barrier (R4-proven). __syncthreads drains vmcnt(0)
    // per wave, so all sc1 h-stores are in the LLC before the slot publish.
    // Wave 0 polls; trailing __syncthreads releases waves 1-3.
    __syncthreads();
    if (wid == 0) {
      if (lane == 0)
        __hip_atomic_store(&slots[blockIdx.x], (unsigned)(wv + 1),
                           __ATOMIC_RELAXED, __HIP_MEMORY_SCOPE_AGENT);
      const unsigned tgt = (unsigned)(wv + 1);
      for (;;) {
        unsigned a, b, c;
        ld_poll3(&slots[lane], &slots[lane + 64], &slots[lane + 128], a, b, c);
        if (__all((a >= tgt) && (b >= tgt) && (c >= tgt))) break;
        __builtin_amdgcn_s_sleep(1);              // ~64 cyc backoff
      }
    }
    __syncthreads();
  }
#undef CONSUME_CHUNK
#undef ISSUE_CHUNK
}

// ======================= fallback: launch-per-wave step =======================
__global__ __launch_bounds__(256) void lstm_step(int wv,
                                                 const bf16* __restrict__ xb,
                                                 const bf16* __restrict__ packed,
                                                 bf16* __restrict__ hbuf,
                                                 float* __restrict__ c_state,
                                                 const float* __restrict__ bias,
                                                 float* __restrict__ out) {
  const int l  = blockIdx.x >> 6;
  const int jt = blockIdx.x & 63;
  const int t  = wv - l;
  if (t < 0 || t >= T_) return;

  const int tid  = threadIdx.x;
  const int wid  = tid >> 6;
  const int lane = tid & 63;
  const int quad = lane >> 4;
  const int lo   = lane & 15;

  const int KB   = (l == 0) ? 42 : 64;
  const int KXb  = (l == 0) ? 10 : 32;
  const int xstr = (l == 0) ? D_ : H_;
  const bf16* xsrc = (l == 0) ? (xb + (size_t)t * (N_ * D_))
                              : (hbuf + (size_t)(l - 1) * 2 * NH + (size_t)(t & 1) * NH);
  const bf16* hsrc = hbuf + (size_t)l * 2 * NH + (size_t)((t - 1) & 1) * NH;
  const size_t lbase = (l == 0) ? 0 : (l == 1 ? 5505024u : 13893632u);
  const int gstr = 64 * KB * 512;
  const bf16* Bb = packed + lbase + (size_t)jt * KB * 512;

  floatx4 acc[2][4];
  const floatx4 zero = {0.f, 0.f, 0.f, 0.f};
#pragma unroll
  for (int mt = 0; mt < 2; ++mt)
#pragma unroll
    for (int g = 0; g < 4; ++g) acc[mt][g] = zero;

  const int arow0 = lo * xstr + quad * 8;
  const int arow1 = (16 + lo) * xstr + quad * 8;
  const int hrow0 = lo * H_ + quad * 8;
  const int hrow1 = (16 + lo) * H_ + quad * 8;

#pragma unroll 2
  for (int kb = wid; kb < KB; kb += 4) {
    bf16x8 a0, a1;
    if (kb < KXb) {
      const bf16* p = xsrc + kb * 32;
      a0 = *(const bf16x8*)(p + arow0);
      a1 = *(const bf16x8*)(p + arow1);
    } else {
      const bf16* p = hsrc + (kb - KXb) * 32;
      a0 = *(const bf16x8*)(p + hrow0);
      a1 = *(const bf16x8*)(p + hrow1);
    }
    const bf16* bp = Bb + kb * 512 + lane * 8;
    bf16x8 b0 = *(const bf16x8*)(bp);
    bf16x8 b1 = *(const bf16x8*)(bp + gstr);
    bf16x8 b2 = *(const bf16x8*)(bp + 2 * gstr);
    bf16x8 b3 = *(const bf16x8*)(bp + 3 * gstr);
    acc[0][0] = __builtin_amdgcn_mfma_f32_16x16x32_bf16(a0, b0, acc[0][0], 0, 0, 0);
    acc[0][1] = __builtin_amdgcn_mfma_f32_16x16x32_bf16(a0, b1, acc[0][1], 0, 0, 0);
    acc[0][2] = __builtin_amdgcn_mfma_f32_16x16x32_bf16(a0, b2, acc[0][2], 0, 0, 0);
    acc[0][3] = __builtin_amdgcn_mfma_f32_16x16x32_bf16(a0, b3, acc[0][3], 0, 0, 0);
    acc[1][0] = __builtin_amdgcn_mfma_f32_16x16x32_bf16(a1, b0, acc[1][0], 0, 0, 0);
    acc[1][1] = __builtin_amdgcn_mfma_f32_16x16x32_bf16(a1, b1, acc[1][1], 0, 0, 0);
    acc[1][2] = __builtin_amdgcn_mfma_f32_16x16x32_bf16(a1, b2, acc[1][2], 0, 0, 0);
    acc[1][3] = __builtin_amdgcn_mfma_f32_16x16x32_bf16(a1, b3, acc[1][3], 0, 0, 0);
  }

  __shared__ float red[4][2][4][4][64];
#pragma unroll
  for (int mt = 0; mt < 2; ++mt)
#pragma unroll
    for (int g = 0; g < 4; ++g)
#pragma unroll
      for (int r = 0; r < 4; ++r) red[wid][mt][g][r][lane] = acc[mt][g][r];
  __syncthreads();
  if (wid != 0) return;

  const int j_h = jt * 16 + lo;
  const float bI = bias[l * 4096 + j_h];
  const float bF = bias[l * 4096 + 1024 + j_h];
  const float bG = bias[l * 4096 + 2048 + j_h];
  const float bO = bias[l * 4096 + 3072 + j_h];
  float* cst = c_state + l * NH;
  bf16* hdst = hbuf + (size_t)l * 2 * NH + (size_t)(t & 1) * NH;

#pragma unroll
  for (int mt = 0; mt < 2; ++mt)
#pragma unroll
    for (int r = 0; r < 4; ++r) {
      const int m = mt * 16 + quad * 4 + r;
      float s0 = 0.f, s1 = 0.f, s2 = 0.f, s3 = 0.f;
#pragma unroll
      for (int w2 = 0; w2 < 4; ++w2) {
        s0 += red[w2][mt][0][r][lane];
        s1 += red[w2][mt][1][r][lane];
        s2 += red[w2][mt][2][r][lane];
        s3 += red[w2][mt][3][r][lane];
      }
      const float ii = sigm(s0 + bI);
      const float ff = sigm(s1 + bF);
      const float gg = tanh_(s2 + bG);
      const float oo = sigm(s3 + bO);
      const int off = m * H_ + j_h;
      const float c = ff * cst[off] + ii * gg;
      cst[off] = c;
      const float h = oo * tanh_(c);
      hdst[off] = (bf16)h;
      if (l == 2) out[(size_t)t * NH + off] = h;
      if (t == T_ - 1) {
        out[32768000 + l * NH + off] = h;
        out[32866304 + l * NH + off] = c;
      }
    }
}

extern "C" void kernel_launch(void* const* d_in, const int* in_sizes, int n_in,
                              void* d_out, int out_size, void* d_ws, size_t ws_size,
                              hipStream_t stream) {
  (void)in_sizes; (void)n_in; (void)out_size;
  const float* x     = (const float*)d_in[0];
  const float* h0    = (const float*)d_in[1];
  const float* c0    = (const float*)d_in[2];
  const float* w_ih0 = (const float*)d_in[3];
  const float* w_ihr = (const float*)d_in[4];
  const float* w_hh  = (const float*)d_in[5];
  const float* b_ih  = (const float*)d_in[6];
  const float* b_hh  = (const float*)d_in[7];
  float* out = (float*)d_out;
  char* ws = (char*)d_ws;

  bf16*     xb      = (bf16*)(ws + 0);
  bf16*     packed  = (bf16*)(ws + 20480000);
  bf16*     hbuf    = (bf16*)(ws + 65044480);
  float*    c_state = (float*)(ws + 65437696);
  float*    bias    = (float*)(ws + 65830912);
  unsigned* slots   = (unsigned*)(ws + 65880064);
  const bool have_slots = ws_size >= 65880064u + 1024u;

  hipLaunchKernelGGL(prep_x, dim3(10000), dim3(256), 0, stream,
                     (const float4*)x, (bf16x4*)xb);
  hipLaunchKernelGGL(prep_pack, dim3(87040), dim3(256), 0, stream,
                     w_ih0, w_ihr, w_hh, packed);
  hipLaunchKernelGGL(prep_state, dim3(384), dim3(256), 0, stream,
                     h0, c0, b_ih, b_hh, hbuf, c_state, bias,
                     have_slots ? slots : (unsigned*)(ws + 65437696));

  const bf16*  xb_c  = (const bf16*)xb;
  const bf16*  pk_c  = (const bf16*)packed;
  bf16*        hb    = hbuf;
  const float* cs_c  = (const float*)c_state;
  const float* bi_c  = (const float*)bias;
  unsigned*    sl    = slots;
  float*       out_p = out;

  hipError_t e = hipErrorUnknown;
  if (have_slots) {
    void* args[7] = {&xb_c, &pk_c, &hb, &cs_c, &bi_c, &sl, &out_p};
    e = hipLaunchCooperativeKernel((const void*)lstm_persist,
                                   dim3(192), dim3(256), args, 0, stream);
  }
  if (e != hipSuccess) {
    (void)hipGetLastError();  // clear error state, fall back to per-wave launches
    for (int wv = 0; wv < T_ + 2; ++wv)
      hipLaunchKernelGGL(lstm_step, dim3(192), dim3(256), 0, stream, wv,
                         xb_c, pk_c, hb, c_state, bias, out);
  }
}

// Round 9
// 8546.757 us; speedup vs baseline: 3.7343x; 1.1888x over previous
//
#include <hip/hip_runtime.h>

// LSTM T=1000 N=32 D=320 H=1024 L=3 on MI355X.
// Persistent cooperative kernel. Hierarchical fence-free grid barrier:
//   publish: per-block slot (192 distinct lines, sc1 store)
//   detect:  block 0 alone scans all slots, then broadcasts per-block flags
//   release: each block polls ITS OWN flag (coalesced 1-line poll)
// -> no shared hot lines; the R8 all-to-all poll (192 blocks x 12 shared lines
//    every ~0.3us) saturated the LLC slices those lines map to and queued every
//    A-load behind it (implied RTT ~5us vs ~0.3us true).
// h exchange: sc0/sc1 write-through stores + sc0/sc1 LLC-coherent loads.
// A-loads: 2-chunk-ahead pipeline (<=16 in flight, no spills, exact vmcnt).
// Weights RESIDENT on-chip: 8 K-iters/wave in VGPRs + 8 K-iters/wave in LDS.
// c-state + bias in registers; epilogue distributed across all 4 waves.
//
// ws layout (bytes):
//   [0,         20480000)  x as bf16            (T*N*320)
//   [20480000,  65044480)  packed B fragments   (22,282,240 bf16)
//   [65044480,  65437696)  h ping-pong bf16     (L * 2 * N*H)
//   [65437696,  65830912)  c state fp32         (L * N*H)
//   [65830912,  65880064)  bias fp32            (L * 4096)
//   [65880064,  65881088)  barrier slots u32    (192 used, 256 zeroed)
//   [65881088,  65882112)  release flags u32    (192 used, 256 zeroed)

#define T_ 1000
#define N_ 32
#define D_ 320
#define H_ 1024
#define NH (N_ * H_)

typedef __bf16 bf16;
typedef bf16 bf16x8 __attribute__((ext_vector_type(8)));
typedef bf16 bf16x4 __attribute__((ext_vector_type(4)));
typedef float floatx4 __attribute__((ext_vector_type(4)));

__device__ __forceinline__ float sigm(float x) { return 1.f / (1.f + __expf(-x)); }
__device__ __forceinline__ float tanh_(float x) {
  float e = __expf(2.f * x);
  return 1.f - 2.f / (e + 1.f);
}

// Issue 8 LLC-coherent 16B loads (L1+L2 bypass), NO waitcnt — caller waits
// with a counted vmcnt tied to the outputs.
__device__ __forceinline__ void ld8_issue(const bf16* p00, const bf16* p01,
                                          const bf16* p10, const bf16* p11,
                                          const bf16* p20, const bf16* p21,
                                          const bf16* p30, const bf16* p31,
                                          bf16x8 A0[4], bf16x8 A1[4]) {
  asm volatile(
      "global_load_dwordx4 %0, %8, off sc0 sc1\n\t"
      "global_load_dwordx4 %1, %9, off sc0 sc1\n\t"
      "global_load_dwordx4 %2, %10, off sc0 sc1\n\t"
      "global_load_dwordx4 %3, %11, off sc0 sc1\n\t"
      "global_load_dwordx4 %4, %12, off sc0 sc1\n\t"
      "global_load_dwordx4 %5, %13, off sc0 sc1\n\t"
      "global_load_dwordx4 %6, %14, off sc0 sc1\n\t"
      "global_load_dwordx4 %7, %15, off sc0 sc1"
      : "=&v"(A0[0]), "=&v"(A1[0]), "=&v"(A0[1]), "=&v"(A1[1]),
        "=&v"(A0[2]), "=&v"(A1[2]), "=&v"(A0[3]), "=&v"(A1[3])
      : "v"(p00), "v"(p01), "v"(p10), "v"(p11),
        "v"(p20), "v"(p21), "v"(p30), "v"(p31)
      : "memory");
}

// Counted wait tied to the chunk's result registers, then a scheduling fence
// so no consumer is hoisted above the wait (guide rule 18).
#define TIE_WAIT(NSTR, Ax, Ay)                                              \
  do {                                                                      \
    asm volatile("s_waitcnt vmcnt(" NSTR ")"                                \
                 : "+v"(Ax[0]), "+v"(Ax[1]), "+v"(Ax[2]), "+v"(Ax[3]),      \
                   "+v"(Ay[0]), "+v"(Ay[1]), "+v"(Ay[2]), "+v"(Ay[3])       \
                 :: "memory");                                              \
    __builtin_amdgcn_sched_barrier(0);                                      \
  } while (0)

// 3 pipelined LLC-coherent 4B loads + waitcnt (block-0 slot scan).
__device__ __forceinline__ void ld_poll3(const unsigned* p0, const unsigned* p1,
                                         const unsigned* p2, unsigned& a,
                                         unsigned& b, unsigned& c) {
  asm volatile(
      "global_load_dword %0, %3, off sc0 sc1\n\t"
      "global_load_dword %1, %4, off sc0 sc1\n\t"
      "global_load_dword %2, %5, off sc0 sc1\n\t"
      "s_waitcnt vmcnt(0)"
      : "=&v"(a), "=&v"(b), "=&v"(c)
      : "v"(p0), "v"(p1), "v"(p2)
      : "memory");
}

// Single LLC-coherent 4B load (own-flag poll; all lanes same addr -> 1 line req).
__device__ __forceinline__ unsigned ld_flag(const unsigned* p) {
  unsigned r;
  asm volatile(
      "global_load_dword %0, %1, off sc0 sc1\n\t"
      "s_waitcnt vmcnt(0)"
      : "=&v"(r) : "v"(p) : "memory");
  return r;
}

// Fire-and-forget LLC write-through 4B store (flag broadcast).
__device__ __forceinline__ void st_flag(unsigned* p, unsigned v) {
  asm volatile("global_store_dword %0, %1, off sc0 sc1" :: "v"(p), "v"(v) : "memory");
}

// Coherent (LLC write-through) 2B store: bypasses the non-coherent XCD L2.
__device__ __forceinline__ void sth(bf16* p, float h) {
  union { __bf16 b; unsigned short s; } u;
  u.b = (__bf16)h;
  unsigned v = u.s;
  asm volatile("global_store_short %0, %1, off sc0 sc1" :: "v"(p), "v"(v) : "memory");
}

// ---- prep: x (fp32) -> bf16 ----
__global__ __launch_bounds__(256) void prep_x(const float4* __restrict__ x,
                                              bf16x4* __restrict__ xb) {
  int idx = blockIdx.x * 256 + threadIdx.x;  // 2,560,000 threads, 4 elems each
  float4 v = x[idx];
  bf16x4 o;
  o[0] = (bf16)v.x; o[1] = (bf16)v.y; o[2] = (bf16)v.z; o[3] = (bf16)v.w;
  xb[idx] = o;
}

// ---- prep: pack W = [w_ih_l ; w_hh_l] (K x 4096) into MFMA B-fragment order.
__global__ __launch_bounds__(256) void prep_pack(const float* __restrict__ w_ih0,
                                                 const float* __restrict__ w_ihr,
                                                 const float* __restrict__ w_hh,
                                                 bf16* __restrict__ packed) {
  int idx = blockIdx.x * 256 + threadIdx.x;  // 22,282,240 total
  int l, r;
  if (idx < 5505024)       { l = 0; r = idx; }
  else if (idx < 13893632) { l = 1; r = idx - 5505024; }
  else                     { l = 2; r = idx - 13893632; }
  const int i    = r & 7;
  const int lane = (r >> 3) & 63;
  const int q    = r >> 9;
  int kb, p;
  if (l == 0) { kb = q % 42; p = q / 42; }   // KB=42 (10 x-blocks + 32 h-blocks)
  else        { kb = q & 63; p = q >> 6; }   // KB=64 (32 + 32)
  const int jt = p & 63;
  const int g  = p >> 6;
  const int k  = kb * 32 + ((lane >> 4) << 3) + i;
  const int j  = (g << 10) + jt * 16 + (lane & 15);
  const int KX = (l == 0) ? 320 : 1024;
  float v;
  if (k < KX) {
    v = (l == 0) ? w_ih0[(size_t)k * 4096 + j]
                 : w_ihr[(size_t)(l - 1) * 4194304 + (size_t)k * 4096 + j];
  } else {
    v = w_hh[(size_t)l * 4194304 + (size_t)(k - KX) * 4096 + j];
  }
  packed[idx] = (bf16)v;
}

// ---- prep: h0 -> hbuf slot 1, c0 -> c_state, bias sum, zero slots+flags
__global__ __launch_bounds__(256) void prep_state(const float* __restrict__ h0,
                                                  const float* __restrict__ c0,
                                                  const float* __restrict__ b_ih,
                                                  const float* __restrict__ b_hh,
                                                  bf16* __restrict__ hbuf,
                                                  float* __restrict__ c_state,
                                                  float* __restrict__ bias,
                                                  unsigned* __restrict__ slots) {
  int idx = blockIdx.x * 256 + threadIdx.x;  // 98,304 threads
  int l = idx >> 15;                         // NH = 32768
  int rem = idx & 32767;
  hbuf[(size_t)l * 2 * NH + NH + rem] = (bf16)h0[idx];
  c_state[idx] = c0[idx];
  if (idx < 12288) bias[idx] = b_ih[idx] + b_hh[idx];
  if (idx < 512) slots[idx] = 0u;            // slots[256] + flags[256]
}

// ======================= persistent cooperative kernel =======================
// grid = 192 blocks (3 layers x 64 j-tiles), 256 threads (4 waves, K-split).
// 1 block/CU. Loop wv = 0..1001; hierarchical slot/flag barrier.
__global__ __launch_bounds__(256, 1) void lstm_persist(
    const bf16* __restrict__ xb, const bf16* __restrict__ packed,
    bf16* hbuf,                     // read AND written (no restrict)
    const float* __restrict__ c_state, const float* __restrict__ bias,
    unsigned* slots, unsigned* flags,
    float* __restrict__ out) {
  const int l  = blockIdx.x >> 6;
  const int jt = blockIdx.x & 63;
  const int tid  = threadIdx.x;
  const int wid  = __builtin_amdgcn_readfirstlane(tid >> 6);  // wave-uniform -> SGPR
  const int lane = tid & 63;
  const int quad = lane >> 4;
  const int lo   = lane & 15;

  const int KB   = (l == 0) ? 42 : 64;
  const int KXb  = (l == 0) ? 10 : 32;
  const int xstr = (l == 0) ? D_ : H_;
  const size_t lbase = (l == 0) ? 0 : (l == 1 ? 5505024u : 13893632u);
  const int gstr = 64 * KB * 512;                 // per-gate stride (elements)
  const bf16* Bb = packed + lbase + (size_t)jt * KB * 512;

  // LDS: weight slice for K-iters n=8..15 (per wave) + cross-wave reduce buffer
  // (3 of 4 rows per wave; each wave keeps its own row r==wid in registers).
  __shared__ bf16x8 wlds[4][8][4][64];            // [wid][n-8][g][lane]  128 KiB
  __shared__ float  red[4][2][4][3][64];          // [wid][mt][g][ri][lane] 24 KiB

  // ---- one-time: weights -> VGPRs (n<8) and LDS (n>=8). Own-wave slice only.
  bf16x8 wreg[8][4];
#pragma unroll
  for (int n = 0; n < 8; ++n) {
    const int kb = wid + 4 * n;
    const bf16* bp = Bb + kb * 512 + lane * 8;
#pragma unroll
    for (int g = 0; g < 4; ++g)
      wreg[n][g] = *(const bf16x8*)(bp + (size_t)g * gstr);
  }
  for (int n = 8; wid + 4 * n < KB; ++n) {
    const int kb = wid + 4 * n;
    const bf16* bp = Bb + kb * 512 + lane * 8;
#pragma unroll
    for (int g = 0; g < 4; ++g)
      wlds[wid][n - 8][g][lane] = *(const bf16x8*)(bp + (size_t)g * gstr);
  }

  // ---- one-time: bias + c into registers. This wave owns rows r = wid.
  const int j_h = jt * 16 + lo;
  const float bI = bias[l * 4096 + j_h];
  const float bF = bias[l * 4096 + 1024 + j_h];
  const float bG = bias[l * 4096 + 2048 + j_h];
  const float bO = bias[l * 4096 + 3072 + j_h];
  float creg[2];
#pragma unroll
  for (int mt = 0; mt < 2; ++mt)
    creg[mt] = c_state[l * NH + (mt * 16 + quad * 4 + wid) * H_ + j_h];

  const int arow0 = lo * xstr + quad * 8;
  const int arow1 = (16 + lo) * xstr + quad * 8;
  const int hrow0 = lo * H_ + quad * 8;
  const int hrow1 = (16 + lo) * H_ + quad * 8;

// issue chunk CH's 8 loads (no wait)
#define ISSUE_CHUNK(CH)                                                          \
  do {                                                                           \
    const bf16 *P0[4], *P1[4];                                                   \
    _Pragma("unroll")                                                            \
    for (int u = 0; u < 4; ++u) {                                                \
      const int kb = wid + 4 * (4 * (CH) + u);                                   \
      const bf16* p;                                                             \
      int r0, r1;                                                                \
      if (kb < KXb)     { p = xsrc + kb * 32;         r0 = arow0; r1 = arow1; }  \
      else if (kb < KB) { p = hsrc + (kb - KXb) * 32; r0 = hrow0; r1 = hrow1; }  \
      else              { p = hsrc;                   r0 = 0;     r1 = 0;     }  \
      P0[u] = p + r0;                                                            \
      P1[u] = p + r1;                                                            \
    }                                                                            \
    ld8_issue(P0[0], P1[0], P0[1], P1[1], P0[2], P1[2], P0[3], P1[3],            \
              A0[CH], A1[CH]);                                                   \
  } while (0)

// one chunk's 8 MFMA x 4 sub-iters (n = 4*CH + u); u unrolled -> static wreg idx
#define CONSUME_CHUNK(CH)                                                        \
  _Pragma("unroll")                                                              \
  for (int u = 0; u < 4; ++u) {                                                  \
    const int n = 4 * (CH) + u;                                                  \
    const int kb = wid + 4 * n;                                                  \
    if (kb < KB) {                                                               \
      bf16x8 b0, b1, b2, b3;                                                     \
      if (n < 8) {                                                               \
        b0 = wreg[n][0]; b1 = wreg[n][1]; b2 = wreg[n][2]; b3 = wreg[n][3];      \
      } else {                                                                   \
        b0 = wlds[wid][n - 8][0][lane];                                          \
        b1 = wlds[wid][n - 8][1][lane];                                          \
        b2 = wlds[wid][n - 8][2][lane];                                          \
        b3 = wlds[wid][n - 8][3][lane];                                          \
      }                                                                          \
      acc[0][0] = __builtin_amdgcn_mfma_f32_16x16x32_bf16(A0[CH][u], b0, acc[0][0], 0, 0, 0); \
      acc[0][1] = __builtin_amdgcn_mfma_f32_16x16x32_bf16(A0[CH][u], b1, acc[0][1], 0, 0, 0); \
      acc[0][2] = __builtin_amdgcn_mfma_f32_16x16x32_bf16(A0[CH][u], b2, acc[0][2], 0, 0, 0); \
      acc[0][3] = __builtin_amdgcn_mfma_f32_16x16x32_bf16(A0[CH][u], b3, acc[0][3], 0, 0, 0); \
      acc[1][0] = __builtin_amdgcn_mfma_f32_16x16x32_bf16(A1[CH][u], b0, acc[1][0], 0, 0, 0); \
      acc[1][1] = __builtin_amdgcn_mfma_f32_16x16x32_bf16(A1[CH][u], b1, acc[1][1], 0, 0, 0); \
      acc[1][2] = __builtin_amdgcn_mfma_f32_16x16x32_bf16(A1[CH][u], b2, acc[1][2], 0, 0, 0); \
      acc[1][3] = __builtin_amdgcn_mfma_f32_16x16x32_bf16(A1[CH][u], b3, acc[1][3], 0, 0, 0); \
    }                                                                            \
  }

  for (int wv = 0; wv < T_ + 2; ++wv) {
    const int t = wv - l;
    if (t >= 0 && t < T_) {                       // block-uniform predicate
      const bf16* xsrc = (l == 0)
          ? (xb + (size_t)t * (N_ * D_))
          : (hbuf + (size_t)(l - 1) * 2 * NH + (size_t)(t & 1) * NH);
      const bf16* hsrc = hbuf + (size_t)l * 2 * NH + (size_t)((t - 1) & 1) * NH;

      floatx4 acc[2][4];
      const floatx4 zero = {0.f, 0.f, 0.f, 0.f};
#pragma unroll
      for (int mt = 0; mt < 2; ++mt)
#pragma unroll
        for (int g = 0; g < 4; ++g) acc[mt][g] = zero;

      // ---- 2-chunk-ahead pipeline: <=16 loads in flight, exact vmcnt counts.
      bf16x8 A0[4][4], A1[4][4];
      if (l == 0) {                               // 3 chunks (KB=42)
        ISSUE_CHUNK(0); ISSUE_CHUNK(1);
        TIE_WAIT("8", A0[0], A1[0]); CONSUME_CHUNK(0); ISSUE_CHUNK(2);
        TIE_WAIT("8", A0[1], A1[1]); CONSUME_CHUNK(1);
        TIE_WAIT("0", A0[2], A1[2]); CONSUME_CHUNK(2);
      } else {                                    // 4 chunks (KB=64)
        ISSUE_CHUNK(0); ISSUE_CHUNK(1);
        TIE_WAIT("8", A0[0], A1[0]); CONSUME_CHUNK(0); ISSUE_CHUNK(2);
        TIE_WAIT("8", A0[1], A1[1]); CONSUME_CHUNK(1); ISSUE_CHUNK(3);
        TIE_WAIT("8", A0[2], A1[2]); CONSUME_CHUNK(2);
        TIE_WAIT("0", A0[3], A1[3]); CONSUME_CHUNK(3);
      }

      // publish partial sums for rows this wave does NOT own (r != wid)
#pragma unroll
      for (int mt = 0; mt < 2; ++mt)
#pragma unroll
        for (int g = 0; g < 4; ++g)
#pragma unroll
          for (int r = 0; r < 4; ++r)
            if (r != wid) red[wid][mt][g][r - (r > wid ? 1 : 0)][lane] = acc[mt][g][r];
      __syncthreads();

      // distributed epilogue: wave `wid` handles rows r = wid (both mt).
      bf16* hdst = hbuf + (size_t)l * 2 * NH + (size_t)(t & 1) * NH;
#pragma unroll
      for (int mt = 0; mt < 2; ++mt) {
        float s[4];
#pragma unroll
        for (int g = 0; g < 4; ++g) {
          float sum = (wid == 0) ? acc[mt][g][0]
                    : (wid == 1) ? acc[mt][g][1]
                    : (wid == 2) ? acc[mt][g][2] : acc[mt][g][3];
#pragma unroll
          for (int w2 = 0; w2 < 4; ++w2)
            if (w2 != wid)
              sum += red[w2][mt][g][wid - (wid > w2 ? 1 : 0)][lane];
          s[g] = sum;
        }
        const float ii = sigm(s[0] + bI);
        const float ff = sigm(s[1] + bF);
        const float gg = tanh_(s[2] + bG);
        const float oo = sigm(s[3] + bO);
        const float c = ff * creg[mt] + ii * gg;
        creg[mt] = c;
        const float h = oo * tanh_(c);
        const int off = (mt * 16 + quad * 4 + wid) * H_ + j_h;
        sth(hdst + off, h);                       // sc0 sc1 write-through to LLC
        if (l == 2) __builtin_nontemporal_store(h, &out[(size_t)t * NH + off]);
        if (t == T_ - 1) {
          __builtin_nontemporal_store(h, &out[32768000 + l * NH + off]);  // hT
          __builtin_nontemporal_store(c, &out[32866304 + l * NH + off]);  // cT
        }
      }
    }

    // ---- hierarchical grid barrier. __syncthreads drains vmcnt(0) per wave,
    // so all sc1 h-stores are in the LLC before the slot publish.
    // Block 0 alone scans slots; everyone polls only their own flag line.
    __syncthreads();
    if (wid == 0) {
      const unsigned tgt = (unsigned)(wv + 1);
      if (lane == 0)
        __hip_atomic_store(&slots[blockIdx.x], tgt,
                           __ATOMIC_RELAXED, __HIP_MEMORY_SCOPE_AGENT);
      if (blockIdx.x == 0) {
        for (;;) {
          unsigned a, b, c;
          ld_poll3(&slots[lane], &slots[lane + 64], &slots[lane + 128], a, b, c);
          if (__all((a >= tgt) && (b >= tgt) && (c >= tgt))) break;
          __builtin_amdgcn_s_sleep(1);            // ~64 cyc backoff
        }
        st_flag(&flags[lane], tgt);               // broadcast release
        st_flag(&flags[lane + 64], tgt);
        st_flag(&flags[lane + 128], tgt);
      }
      for (;;) {                                  // own-flag poll (1 line req)
        unsigned f = ld_flag(&flags[blockIdx.x]);
        if (f >= tgt) break;
        __builtin_amdgcn_s_sleep(1);
      }
    }
    __syncthreads();
  }
#undef CONSUME_CHUNK
#undef ISSUE_CHUNK
}

// ======================= fallback: launch-per-wave step =======================
__global__ __launch_bounds__(256) void lstm_step(int wv,
                                                 const bf16* __restrict__ xb,
                                                 const bf16* __restrict__ packed,
                                                 bf16* __restrict__ hbuf,
                                                 float* __restrict__ c_state,
                                                 const float* __restrict__ bias,
                                                 float* __restrict__ out) {
  const int l  = blockIdx.x >> 6;
  const int jt = blockIdx.x & 63;
  const int t  = wv - l;
  if (t < 0 || t >= T_) return;

  const int tid  = threadIdx.x;
  const int wid  = tid >> 6;
  const int lane = tid & 63;
  const int quad = lane >> 4;
  const int lo   = lane & 15;

  const int KB   = (l == 0) ? 42 : 64;
  const int KXb  = (l == 0) ? 10 : 32;
  const int xstr = (l == 0) ? D_ : H_;
  const bf16* xsrc = (l == 0) ? (xb + (size_t)t * (N_ * D_))
                              : (hbuf + (size_t)(l - 1) * 2 * NH + (size_t)(t & 1) * NH);
  const bf16* hsrc = hbuf + (size_t)l * 2 * NH + (size_t)((t - 1) & 1) * NH;
  const size_t lbase = (l == 0) ? 0 : (l == 1 ? 5505024u : 13893632u);
  const int gstr = 64 * KB * 512;
  const bf16* Bb = packed + lbase + (size_t)jt * KB * 512;

  floatx4 acc[2][4];
  const floatx4 zero = {0.f, 0.f, 0.f, 0.f};
#pragma unroll
  for (int mt = 0; mt < 2; ++mt)
#pragma unroll
    for (int g = 0; g < 4; ++g) acc[mt][g] = zero;

  const int arow0 = lo * xstr + quad * 8;
  const int arow1 = (16 + lo) * xstr + quad * 8;
  const int hrow0 = lo * H_ + quad * 8;
  const int hrow1 = (16 + lo) * H_ + quad * 8;

#pragma unroll 2
  for (int kb = wid; kb < KB; kb += 4) {
    bf16x8 a0, a1;
    if (kb < KXb) {
      const bf16* p = xsrc + kb * 32;
      a0 = *(const bf16x8*)(p + arow0);
      a1 = *(const bf16x8*)(p + arow1);
    } else {
      const bf16* p = hsrc + (kb - KXb) * 32;
      a0 = *(const bf16x8*)(p + hrow0);
      a1 = *(const bf16x8*)(p + hrow1);
    }
    const bf16* bp = Bb + kb * 512 + lane * 8;
    bf16x8 b0 = *(const bf16x8*)(bp);
    bf16x8 b1 = *(const bf16x8*)(bp + gstr);
    bf16x8 b2 = *(const bf16x8*)(bp + 2 * gstr);
    bf16x8 b3 = *(const bf16x8*)(bp + 3 * gstr);
    acc[0][0] = __builtin_amdgcn_mfma_f32_16x16x32_bf16(a0, b0, acc[0][0], 0, 0, 0);
    acc[0][1] = __builtin_amdgcn_mfma_f32_16x16x32_bf16(a0, b1, acc[0][1], 0, 0, 0);
    acc[0][2] = __builtin_amdgcn_mfma_f32_16x16x32_bf16(a0, b2, acc[0][2], 0, 0, 0);
    acc[0][3] = __builtin_amdgcn_mfma_f32_16x16x32_bf16(a0, b3, acc[0][3], 0, 0, 0);
    acc[1][0] = __builtin_amdgcn_mfma_f32_16x16x32_bf16(a1, b0, acc[1][0], 0, 0, 0);
    acc[1][1] = __builtin_amdgcn_mfma_f32_16x16x32_bf16(a1, b1, acc[1][1], 0, 0, 0);
    acc[1][2] = __builtin_amdgcn_mfma_f32_16x16x32_bf16(a1, b2, acc[1][2], 0, 0, 0);
    acc[1][3] = __builtin_amdgcn_mfma_f32_16x16x32_bf16(a1, b3, acc[1][3], 0, 0, 0);
  }

  __shared__ float red[4][2][4][4][64];
#pragma unroll
  for (int mt = 0; mt < 2; ++mt)
#pragma unroll
    for (int g = 0; g < 4; ++g)
#pragma unroll
      for (int r = 0; r < 4; ++r) red[wid][mt][g][r][lane] = acc[mt][g][r];
  __syncthreads();
  if (wid != 0) return;

  const int j_h = jt * 16 + lo;
  const float bI = bias[l * 4096 + j_h];
  const float bF = bias[l * 4096 + 1024 + j_h];
  const float bG = bias[l * 4096 + 2048 + j_h];
  const float bO = bias[l * 4096 + 3072 + j_h];
  float* cst = c_state + l * NH;
  bf16* hdst = hbuf + (size_t)l * 2 * NH + (size_t)(t & 1) * NH;

#pragma unroll
  for (int mt = 0; mt < 2; ++mt)
#pragma unroll
    for (int r = 0; r < 4; ++r) {
      const int m = mt * 16 + quad * 4 + r;
      float s0 = 0.f, s1 = 0.f, s2 = 0.f, s3 = 0.f;
#pragma unroll
      for (int w2 = 0; w2 < 4; ++w2) {
        s0 += red[w2][mt][0][r][lane];
        s1 += red[w2][mt][1][r][lane];
        s2 += red[w2][mt][2][r][lane];
        s3 += red[w2][mt][3][r][lane];
      }
      const float ii = sigm(s0 + bI);
      const float ff = sigm(s1 + bF);
      const float gg = tanh_(s2 + bG);
      const float oo = sigm(s3 + bO);
      const int off = m * H_ + j_h;
      const float c = ff * cst[off] + ii * gg;
      cst[off] = c;
      const float h = oo * tanh_(c);
      hdst[off] = (bf16)h;
      if (l == 2) out[(size_t)t * NH + off] = h;
      if (t == T_ - 1) {
        out[32768000 + l * NH + off] = h;
        out[32866304 + l * NH + off] = c;
      }
    }
}

extern "C" void kernel_launch(void* const* d_in, const int* in_sizes, int n_in,
                              void* d_out, int out_size, void* d_ws, size_t ws_size,
                              hipStream_t stream) {
  (void)in_sizes; (void)n_in; (void)out_size;
  const float* x     = (const float*)d_in[0];
  const float* h0    = (const float*)d_in[1];
  const float* c0    = (const float*)d_in[2];
  const float* w_ih0 = (const float*)d_in[3];
  const float* w_ihr = (const float*)d_in[4];
  const float* w_hh  = (const float*)d_in[5];
  const float* b_ih  = (const float*)d_in[6];
  const float* b_hh  = (const float*)d_in[7];
  float* out = (float*)d_out;
  char* ws = (char*)d_ws;

  bf16*     xb      = (bf16*)(ws + 0);
  bf16*     packed  = (bf16*)(ws + 20480000);
  bf16*     hbuf    = (bf16*)(ws + 65044480);
  float*    c_state = (float*)(ws + 65437696);
  float*    bias    = (float*)(ws + 65830912);
  unsigned* slots   = (unsigned*)(ws + 65880064);
  unsigned* flags   = (unsigned*)(ws + 65881088);
  const bool have_slots = ws_size >= 65880064u + 2048u;

  hipLaunchKernelGGL(prep_x, dim3(10000), dim3(256), 0, stream,
                     (const float4*)x, (bf16x4*)xb);
  hipLaunchKernelGGL(prep_pack, dim3(87040), dim3(256), 0, stream,
                     w_ih0, w_ihr, w_hh, packed);
  hipLaunchKernelGGL(prep_state, dim3(384), dim3(256), 0, stream,
                     h0, c0, b_ih, b_hh, hbuf, c_state, bias,
                     have_slots ? slots : (unsigned*)(ws + 65437696));

  const bf16*  xb_c  = (const bf16*)xb;
  const bf16*  pk_c  = (const bf16*)packed;
  bf16*        hb    = hbuf;
  const float* cs_c  = (const float*)c_state;
  const float* bi_c  = (const float*)bias;
  unsigned*    sl    = slots;
  unsigned*    fl    = flags;
  float*       out_p = out;

  hipError_t e = hipErrorUnknown;
  if (have_slots) {
    void* args[8] = {&xb_c, &pk_c, &hb, &cs_c, &bi_c, &sl, &fl, &out_p};
    e = hipLaunchCooperativeKernel((const void*)lstm_persist,
                                   dim3(192), dim3(256), args, 0, stream);
  }
  if (e != hipSuccess) {
    (void)hipGetLastError();  // clear error state, fall back to per-wave launches
    for (int wv = 0; wv < T_ + 2; ++wv)
      hipLaunchKernelGGL(lstm_step, dim3(192), dim3(256), 0, stream, wv,
                         xb_c, pk_c, hb, c_state, bias, out);
  }
}